// Round 13
// baseline (943.840 us; speedup 1.0000x reference)
//
#include <hip/hip_runtime.h>
#include <hip/hip_bf16.h>

// Problem constants (match reference setup_inputs)
constexpr int N_NODES = 100000;
constexpr int N_EDGES = 20000;
constexpr int NNZ     = 3200000;
constexpr int F_IN    = 512;
constexpr int HID     = 64;
constexpr int CLS     = 70;

// CSR build via two-level counting sort, both directions fused.
constexpr int CHUNK = 32768;                         // entries per partition block
constexpr int NBA   = (NNZ + CHUNK - 1) / CHUNK;     // 98 partition blocks
constexpr int NBUK0 = (N_EDGES + 63) / 64;           // 313
constexpr int NBUK1 = (N_NODES + 127) / 128;         // 782
constexpr int NH0   = NBUK0 * NBA;                   // 30674
constexpr int NH1   = NBUK1 * NBA;                   // 76636
constexpr int NHT   = NH0 + NH1;                     // 107310 (concatenated)

// ---------------------------------------------------------------------------
// Pass A1 (fused): per-block LDS histograms for BOTH directions, one pass.
// ---------------------------------------------------------------------------
__global__ __launch_bounds__(256) void part_hist_both(const int* __restrict__ hidx,
                                                      int* __restrict__ hist) {
    __shared__ int cnt[NBUK0 + NBUK1];
    for (int b = threadIdx.x; b < NBUK0 + NBUK1; b += 256) cnt[b] = 0;
    __syncthreads();
    int base = blockIdx.x * CHUNK;
    int lim = NNZ - base; if (lim > CHUNK) lim = CHUNK;
    for (int i = threadIdx.x; i < lim; i += 256) {
        int s = hidx[base + i];
        int e = hidx[NNZ + base + i];
        atomicAdd(&cnt[e >> 6], 1);
        atomicAdd(&cnt[NBUK0 + (s >> 7)], 1);
    }
    __syncthreads();
    for (int b = threadIdx.x; b < NBUK0; b += 256)
        hist[b * NBA + blockIdx.x] = cnt[b];
    for (int b = threadIdx.x; b < NBUK1; b += 256)
        hist[NH0 + b * NBA + blockIdx.x] = cnt[NBUK0 + b];
}

// ---------------------------------------------------------------------------
// Generic exclusive scan: scan_blocks -> scan_bsums -> scan_apply
// ---------------------------------------------------------------------------
__global__ __launch_bounds__(256) void scan_blocks(const int* __restrict__ in,
                                                   int* __restrict__ out,
                                                   int* __restrict__ bsum, int n) {
    __shared__ int tmp[256];
    int base = blockIdx.x * 2048;
    int vals[8];
    int s = 0;
#pragma unroll
    for (int i = 0; i < 8; ++i) {
        int g = base + threadIdx.x * 8 + i;
        int v = (g < n) ? in[g] : 0;
        s += v;
        vals[i] = s;
    }
    tmp[threadIdx.x] = s;
    __syncthreads();
    for (int off = 1; off < 256; off <<= 1) {
        int v = 0;
        if (threadIdx.x >= off) v = tmp[threadIdx.x - off];
        __syncthreads();
        if (threadIdx.x >= off) tmp[threadIdx.x] += v;
        __syncthreads();
    }
    int prev = (threadIdx.x > 0) ? tmp[threadIdx.x - 1] : 0;
#pragma unroll
    for (int i = 0; i < 8; ++i) {
        int g = base + threadIdx.x * 8 + i;
        if (g < n) out[g + 1] = vals[i] + prev;
    }
    if (threadIdx.x == 255) bsum[blockIdx.x] = tmp[255];
}

__global__ __launch_bounds__(64) void scan_bsums(int* __restrict__ bsum, int nb) {
    int t = threadIdx.x;
    int v = (t < nb) ? bsum[t] : 0;
#pragma unroll
    for (int off = 1; off < 64; off <<= 1) {
        int u = __shfl_up(v, off);
        if (t >= off) v += u;
    }
    int ex = __shfl_up(v, 1);
    if (t == 0) ex = 0;
    if (t < nb) bsum[t] = ex;
}

__global__ __launch_bounds__(256) void scan_apply(int* __restrict__ out,
                                                  const int* __restrict__ bsum, int n) {
    int g = blockIdx.x * 256 + threadIdx.x;
    if (g >= n) return;
    out[g + 1] += bsum[g >> 11];
    if (g == 0) out[0] = 0;
}

// ---------------------------------------------------------------------------
// Pass A2 (fused): scatter BOTH packed directions in one pass over hidx.
// ---------------------------------------------------------------------------
__global__ __launch_bounds__(256) void part_scatter_both(const int* __restrict__ hidx,
                                                         const int* __restrict__ scanned,
                                                         unsigned* __restrict__ bucketed) {
    __shared__ int cur[NBUK0 + NBUK1];
    for (int b = threadIdx.x; b < NBUK0; b += 256)
        cur[b] = scanned[b * NBA + blockIdx.x];
    for (int b = threadIdx.x; b < NBUK1; b += 256)
        cur[NBUK0 + b] = scanned[NH0 + b * NBA + blockIdx.x];
    __syncthreads();
    int base = blockIdx.x * CHUNK;
    int lim = NNZ - base; if (lim > CHUNK) lim = CHUNK;
    for (int i = threadIdx.x; i < lim; i += 256) {
        int s = hidx[base + i];
        int e = hidx[NNZ + base + i];
        int pos0 = atomicAdd(&cur[e >> 6], 1);
        bucketed[pos0] = ((unsigned)e << 17) | (unsigned)s;
        int pos1 = atomicAdd(&cur[NBUK0 + (s >> 7)], 1);
        bucketed[pos1] = ((unsigned)s << 15) | (unsigned)e;
    }
}

// ---------------------------------------------------------------------------
// Pass B, dir0 with GRANULE SORT (validated R11/R12)
// ---------------------------------------------------------------------------
__global__ __launch_bounds__(256) void bucket_build0(const unsigned* __restrict__ bucketed,
                                                     const int* __restrict__ sc,
                                                     int* __restrict__ ptr_out,
                                                     float* __restrict__ inv_out,
                                                     int* __restrict__ list) {
    constexpr int NSB = 64 * 16;        // 1024 (edge_local, node>>13) keys
    __shared__ int kcnt[NSB];
    __shared__ int koff[NSB + 1];
    __shared__ int kcur[NSB];
    __shared__ int tmp[256];
    int bucket = blockIdx.x;
    int start = sc[bucket * NBA];
    int end   = sc[(bucket + 1) * NBA];
    for (int k = threadIdx.x; k < NSB; k += 256) kcnt[k] = 0;
    __syncthreads();
    for (int i = start + threadIdx.x; i < end; i += 256) {
        unsigned p = bucketed[i];
        int e_loc = (int)((p >> 17) & 63u);
        int n     = (int)(p & 0x1FFFFu);
        atomicAdd(&kcnt[e_loc * 16 + (n >> 13)], 1);
    }
    __syncthreads();
    int b4 = threadIdx.x * 4;
    int v0 = kcnt[b4], v1 = kcnt[b4 + 1], v2 = kcnt[b4 + 2], v3 = kcnt[b4 + 3];
    int s = v0 + v1 + v2 + v3;
    tmp[threadIdx.x] = s;
    __syncthreads();
    for (int off = 1; off < 256; off <<= 1) {
        int u = 0;
        if (threadIdx.x >= off) u = tmp[threadIdx.x - off];
        __syncthreads();
        if (threadIdx.x >= off) tmp[threadIdx.x] += u;
        __syncthreads();
    }
    int prev = (threadIdx.x > 0) ? tmp[threadIdx.x - 1] : 0;
    koff[b4]     = prev;
    koff[b4 + 1] = prev + v0;
    koff[b4 + 2] = prev + v0 + v1;
    koff[b4 + 3] = prev + v0 + v1 + v2;
    if (threadIdx.x == 255) koff[NSB] = tmp[255];
    __syncthreads();
    if (threadIdx.x < 64) {
        int key = bucket * 64 + threadIdx.x;
        if (key < N_EDGES) {
            int o0 = koff[threadIdx.x * 16];
            int o1 = koff[threadIdx.x * 16 + 16];
            ptr_out[key] = start + o0;
            int d = o1 - o0;
            inv_out[key] = (d > 0) ? 1.0f / (float)d : 0.0f;
        }
    }
    for (int k = threadIdx.x; k < NSB; k += 256) kcur[k] = start + koff[k];
    __syncthreads();
    for (int i = start + threadIdx.x; i < end; i += 256) {
        unsigned p = bucketed[i];
        int e_loc = (int)((p >> 17) & 63u);
        int n     = (int)(p & 0x1FFFFu);
        int pos = atomicAdd(&kcur[e_loc * 16 + (n >> 13)], 1);
        list[pos] = n;
    }
    if (bucket == NBUK0 - 1 && threadIdx.x == 0) ptr_out[N_EDGES] = NNZ;
}

// ---------------------------------------------------------------------------
// Pass B, dir1 (validated; tail folded in)
// ---------------------------------------------------------------------------
__global__ __launch_bounds__(256) void bucket_build1(const unsigned* __restrict__ bucketed,
                                                     const int* __restrict__ sc,
                                                     int* __restrict__ ptr_out,
                                                     float* __restrict__ inv_out,
                                                     int* __restrict__ list, int sub) {
    constexpr int KB = 128;
    __shared__ int kcnt[KB];
    __shared__ int koff[KB + 1];
    __shared__ int kcur[KB];
    int bucket = blockIdx.x;
    int start = sc[bucket * NBA];
    int end   = sc[(bucket + 1) * NBA];
    for (int k = threadIdx.x; k < KB; k += 256) kcnt[k] = 0;
    __syncthreads();
    for (int i = start + threadIdx.x; i < end; i += 256) {
        int kl = (int)((bucketed[i] >> 15) & (unsigned)(KB - 1));
        atomicAdd(&kcnt[kl], 1);
    }
    __syncthreads();
    if (threadIdx.x == 0) {
        int s = 0;
#pragma unroll 8
        for (int k = 0; k < KB; ++k) { koff[k] = s; s += kcnt[k]; }
        koff[KB] = s;
    }
    __syncthreads();
    if (threadIdx.x < KB) {
        int key = bucket * KB + threadIdx.x;
        int base = start + koff[threadIdx.x];
        if (key < N_NODES) {
            ptr_out[key] = base - sub;
            int d = kcnt[threadIdx.x];
            inv_out[key] = (d > 0) ? 1.0f / (float)d : 0.0f;
        }
        kcur[threadIdx.x] = base;
    }
    __syncthreads();
    for (int i = start + threadIdx.x; i < end; i += 256) {
        unsigned p = bucketed[i];
        int kl = (int)((p >> 15) & (unsigned)(KB - 1));
        int pos = atomicAdd(&kcur[kl], 1);
        list[pos - sub] = (int)(p & 0x7FFFu);
    }
    if (bucket == NBUK1 - 1 && threadIdx.x == 0) ptr_out[N_NODES] = NNZ;
}

// ---------------------------------------------------------------------------
// GEMM1: C[M][64] = A[M][512] @ B[512][64]  (fp32)
// R9 structure + REGISTER DOUBLE-BUFFER: tile t+1's global loads (4 float4
// in regs) issue right after the first barrier, hiding ~500cy global latency
// under tile t's 512-FMA block. LDS 17.9KB -> 8 blocks/CU unchanged.
// ---------------------------------------------------------------------------
__global__ __launch_bounds__(256, 8) void gemm1_kernel(const float* __restrict__ A,
                                                       const float* __restrict__ B,
                                                       float* __restrict__ C, int M) {
    constexpr int BK = 32;
    __shared__ __align__(16) float Ast[64][BK + 4];   // row-major, stride 36
    __shared__ __align__(16) float Bs[BK][HID + 4];   // k-major, stride 68
    int tid = threadIdx.x;
    int tx = tid & 15;
    int ty = tid >> 4;
    int row0 = blockIdx.x * 64;
    float acc[4][4] = {};
    int a_row = tid >> 3;               // 0..31
    int a_c4  = (tid & 7) * 4;
    int b_k   = tid >> 4;               // 0..15
    int b_c   = (tid & 15) * 4;
    float4 rA[2], rB[2];
#pragma unroll
    for (int l = 0; l < 2; ++l) {       // prologue: tile 0 -> regs
        int grow = row0 + a_row + 32 * l;
        rA[l] = make_float4(0.f, 0.f, 0.f, 0.f);
        if (grow < M) rA[l] = *reinterpret_cast<const float4*>(&A[(size_t)grow * F_IN + a_c4]);
        rB[l] = *reinterpret_cast<const float4*>(&B[(size_t)(b_k + 16 * l) * HID + b_c]);
    }
    for (int k0 = 0; k0 < F_IN; k0 += BK) {
#pragma unroll
        for (int l = 0; l < 2; ++l) {   // regs -> LDS
            *reinterpret_cast<float4*>(&Ast[a_row + 32 * l][a_c4]) = rA[l];
            *reinterpret_cast<float4*>(&Bs[b_k + 16 * l][b_c]) = rB[l];
        }
        __syncthreads();
        int kn = k0 + BK;
        if (kn < F_IN) {                // issue NEXT tile's global loads now
#pragma unroll
            for (int l = 0; l < 2; ++l) {
                int grow = row0 + a_row + 32 * l;
                rA[l] = make_float4(0.f, 0.f, 0.f, 0.f);
                if (grow < M) rA[l] = *reinterpret_cast<const float4*>(&A[(size_t)grow * F_IN + kn + a_c4]);
                rB[l] = *reinterpret_cast<const float4*>(&B[(size_t)(kn + b_k + 16 * l) * HID + b_c]);
            }
        }
#pragma unroll
        for (int k = 0; k < BK; k += 4) {
            float4 a0 = *reinterpret_cast<const float4*>(&Ast[ty * 4 + 0][k]);
            float4 a1 = *reinterpret_cast<const float4*>(&Ast[ty * 4 + 1][k]);
            float4 a2 = *reinterpret_cast<const float4*>(&Ast[ty * 4 + 2][k]);
            float4 a3 = *reinterpret_cast<const float4*>(&Ast[ty * 4 + 3][k]);
            float4 b0 = *reinterpret_cast<const float4*>(&Bs[k + 0][tx * 4]);
            float4 b1 = *reinterpret_cast<const float4*>(&Bs[k + 1][tx * 4]);
            float4 b2 = *reinterpret_cast<const float4*>(&Bs[k + 2][tx * 4]);
            float4 b3 = *reinterpret_cast<const float4*>(&Bs[k + 3][tx * 4]);
            float a[4][4] = {{a0.x, a0.y, a0.z, a0.w},
                             {a1.x, a1.y, a1.z, a1.w},
                             {a2.x, a2.y, a2.z, a2.w},
                             {a3.x, a3.y, a3.z, a3.w}};
            float b[4][4] = {{b0.x, b0.y, b0.z, b0.w},
                             {b1.x, b1.y, b1.z, b1.w},
                             {b2.x, b2.y, b2.z, b2.w},
                             {b3.x, b3.y, b3.z, b3.w}};
#pragma unroll
            for (int s = 0; s < 4; ++s)
#pragma unroll
                for (int i = 0; i < 4; ++i)
#pragma unroll
                    for (int j = 0; j < 4; ++j)
                        acc[i][j] += a[i][s] * b[s][j];
        }
        __syncthreads();
    }
#pragma unroll
    for (int i = 0; i < 4; ++i) {
        int row = row0 + ty * 4 + i;
        if (row < M) {
            float4 v = make_float4(acc[i][0], acc[i][1], acc[i][2], acc[i][3]);
            *reinterpret_cast<float4*>(&C[(size_t)row * HID + tx * 4]) = v;
        }
    }
}

// ---------------------------------------------------------------------------
// Segment gather-sum: wave/segment, 4 groups of 16 lanes. DEPTH-4 path for
// full 64-row batches (16 loads in flight/lane, fully unrolled -> registers)
// + depth-2/1 for partial batches; NEXT-batch list prefetch hides the serial
// list-load->shuffle dependency. All shuffles uniform across 64 lanes.
// ---------------------------------------------------------------------------
template <int PHASE>
__global__ __launch_bounds__(256) void seg_gather(const float* __restrict__ in,
                                                  float* __restrict__ out,
                                                  const int* __restrict__ ptr,
                                                  const int* __restrict__ list,
                                                  const float* __restrict__ scale,
                                                  const float* __restrict__ bias,
                                                  int nseg, int do_relu) {
    int gid = blockIdx.x * 256 + threadIdx.x;
    int seg = gid >> 6;
    int lane = gid & 63;
    if (seg >= nseg) return;
    int beg = ptr[seg], end = ptr[seg + 1];
    int g = lane >> 4, sub = lane & 15;
    const float4* in4 = reinterpret_cast<const float4*>(in);
    float4 acc = make_float4(0.f, 0.f, 0.f, 0.f);
    int cnt0 = end - beg; if (cnt0 > 64) cnt0 = 64;
    int idx = (lane < cnt0) ? list[beg + lane] : 0;
    for (int j = beg; j < end; j += 64) {
        int cnt = end - j; if (cnt > 64) cnt = 64;        // wave-uniform
        // prefetch next batch's indices (hides under this batch's gathers)
        int nj = j + 64;
        int idx_next = 0;
        if (nj < end) {
            int ncnt = end - nj; if (ncnt > 64) ncnt = 64;
            if (lane < ncnt) idx_next = list[nj + lane];
        }
        int full16 = cnt >> 4;
        int s = 0;
        for (; s + 4 <= full16; s += 4) {                 // full 64-row batch
            int r0 = 16 * s + g;
            int n[16];
            float4 v[16];
#pragma unroll
            for (int q = 0; q < 16; ++q) n[q] = __shfl(idx, r0 + 4 * q);
#pragma unroll
            for (int q = 0; q < 16; ++q) v[q] = in4[(size_t)n[q] * 16 + sub];
#pragma unroll
            for (int q = 0; q < 16; ++q) {
                acc.x += v[q].x; acc.y += v[q].y; acc.z += v[q].z; acc.w += v[q].w;
            }
        }
        for (; s + 2 <= full16; s += 2) {                 // 32 rows in flight
            int r0 = 16 * s + g;
            int n0 = __shfl(idx, r0);
            int n1 = __shfl(idx, r0 + 4);
            int n2 = __shfl(idx, r0 + 8);
            int n3 = __shfl(idx, r0 + 12);
            int n4 = __shfl(idx, r0 + 16);
            int n5 = __shfl(idx, r0 + 20);
            int n6 = __shfl(idx, r0 + 24);
            int n7 = __shfl(idx, r0 + 28);
            float4 v0 = in4[(size_t)n0 * 16 + sub];
            float4 v1 = in4[(size_t)n1 * 16 + sub];
            float4 v2 = in4[(size_t)n2 * 16 + sub];
            float4 v3 = in4[(size_t)n3 * 16 + sub];
            float4 v4 = in4[(size_t)n4 * 16 + sub];
            float4 v5 = in4[(size_t)n5 * 16 + sub];
            float4 v6 = in4[(size_t)n6 * 16 + sub];
            float4 v7 = in4[(size_t)n7 * 16 + sub];
            acc.x += (v0.x + v1.x) + (v2.x + v3.x);
            acc.y += (v0.y + v1.y) + (v2.y + v3.y);
            acc.z += (v0.z + v1.z) + (v2.z + v3.z);
            acc.w += (v0.w + v1.w) + (v2.w + v3.w);
            acc.x += (v4.x + v5.x) + (v6.x + v7.x);
            acc.y += (v4.y + v5.y) + (v6.y + v7.y);
            acc.z += (v4.z + v5.z) + (v6.z + v7.z);
            acc.w += (v4.w + v5.w) + (v6.w + v7.w);
        }
        for (; s < full16; ++s) {
            int r0 = 16 * s + g;
            int n0 = __shfl(idx, r0);
            int n1 = __shfl(idx, r0 + 4);
            int n2 = __shfl(idx, r0 + 8);
            int n3 = __shfl(idx, r0 + 12);
            float4 v0 = in4[(size_t)n0 * 16 + sub];
            float4 v1 = in4[(size_t)n1 * 16 + sub];
            float4 v2 = in4[(size_t)n2 * 16 + sub];
            float4 v3 = in4[(size_t)n3 * 16 + sub];
            acc.x += (v0.x + v1.x) + (v2.x + v3.x);
            acc.y += (v0.y + v1.y) + (v2.y + v3.y);
            acc.z += (v0.z + v1.z) + (v2.z + v3.z);
            acc.w += (v0.w + v1.w) + (v2.w + v3.w);
        }
        int rem_start = full16 << 4;
        int nrem4 = (cnt - rem_start + 3) >> 2;
        for (int t = 0; t < nrem4; ++t) {
            int row = rem_start + 4 * t + g;
            int n = __shfl(idx, row < cnt ? row : 0);
            if (row < cnt) {
                float4 v = in4[(size_t)n * 16 + sub];
                acc.x += v.x; acc.y += v.y; acc.z += v.z; acc.w += v.w;
            }
        }
        idx = idx_next;
    }
    acc.x += __shfl_xor(acc.x, 16);
    acc.y += __shfl_xor(acc.y, 16);
    acc.z += __shfl_xor(acc.z, 16);
    acc.w += __shfl_xor(acc.w, 16);
    acc.x += __shfl_xor(acc.x, 32);
    acc.y += __shfl_xor(acc.y, 32);
    acc.z += __shfl_xor(acc.z, 32);
    acc.w += __shfl_xor(acc.w, 32);
    if (lane < 16) {
        float s = scale[seg];
        acc.x *= s; acc.y *= s; acc.z *= s; acc.w *= s;
        if (bias) {
            float4 b = reinterpret_cast<const float4*>(bias)[sub];
            acc.x += b.x; acc.y += b.y; acc.z += b.z; acc.w += b.w;
        }
        if (do_relu) {
            acc.x = fmaxf(acc.x, 0.f); acc.y = fmaxf(acc.y, 0.f);
            acc.z = fmaxf(acc.z, 0.f); acc.w = fmaxf(acc.w, 0.f);
        }
        reinterpret_cast<float4*>(out)[(size_t)seg * 16 + sub] = acc;
    }
}

// ---------------------------------------------------------------------------
// GEMM2 epilogue: out[M][70] = in[M][64] @ W2[64][70] + b2  (wave per row)
// (kept separate — R11 showed fusion into phase 3 regresses)
// ---------------------------------------------------------------------------
__global__ __launch_bounds__(256) void gemm2_kernel(const float* __restrict__ in,
                                                    const float* __restrict__ W2,
                                                    const float* __restrict__ b2,
                                                    float* __restrict__ out, int M) {
    __shared__ float Ws[HID][72];
    __shared__ float bs[72];
    __shared__ float rows[4][HID];
    int tid = threadIdx.x;
    for (int i = tid; i < HID * 72; i += 256) {
        int r = i / 72, c = i % 72;
        Ws[r][c] = (c < CLS) ? W2[r * CLS + c] : 0.f;
    }
    if (tid < 72) bs[tid] = (tid < CLS) ? b2[tid] : 0.f;
    int wid = tid >> 6, lane = tid & 63;
    int m = blockIdx.x * 4 + wid;
    if (m < M) rows[wid][lane] = in[(size_t)m * HID + lane];
    __syncthreads();
    if (m >= M) return;
    int c2 = 64 + (lane & 7);
    float acc0 = bs[lane];
    float acc1 = bs[c2];
#pragma unroll
    for (int k = 0; k < HID; ++k) {
        float xv = rows[wid][k];
        acc0 += xv * Ws[k][lane];
        acc1 += xv * Ws[k][c2];
    }
    out[(size_t)m * CLS + lane] = acc0;
    if (lane < 6) out[(size_t)m * CLS + 64 + lane] = acc1;
}

// ---------------------------------------------------------------------------
extern "C" void kernel_launch(void* const* d_in, const int* in_sizes, int n_in,
                              void* d_out, int out_size, void* d_ws, size_t ws_size,
                              hipStream_t stream) {
    const float* x   = (const float*)d_in[0];
    const int*   hid = (const int*)d_in[1];     // [2][NNZ] int32: row0=node, row1=edge
    const float* W1  = (const float*)d_in[2];
    const float* b1  = (const float*)d_in[3];
    const float* W2  = (const float*)d_in[4];
    const float* b2  = (const float*)d_in[5];
    float* out = (float*)d_out;

    size_t off = 0;
    auto alloc = [&](size_t bytes) {
        void* p = (char*)d_ws + off;
        off += (bytes + 255) & ~(size_t)255;
        return p;
    };
    int*   ptr1  = (int*)alloc((size_t)(N_EDGES + 1) * 4);
    int*   ptr2  = (int*)alloc((size_t)(N_NODES + 1) * 4);
    int*   bsum  = (int*)alloc(64 * 4);
    float* Binv  = (float*)alloc((size_t)N_EDGES * 4);
    float* Dinv  = (float*)alloc((size_t)N_NODES * 4);
    int*   list1 = (int*)alloc((size_t)NNZ * 4);
    int*   list2 = (int*)alloc((size_t)NNZ * 4);
    float* bufA  = (float*)alloc((size_t)N_NODES * HID * 4);   // xW1, later agg2
    float* bufB  = (float*)alloc((size_t)N_NODES * HID * 4);   // h1 (relu'd)
    float* he    = (float*)alloc((size_t)N_EDGES * HID * 4);   // edge features
    (void)ws_size; (void)n_in; (void)in_sizes; (void)out_size;

    // Build-time scratch aliases (regions only written after the build):
    int*      hist     = (int*)he;
    int*      scanned  = (int*)((char*)he + (512 << 10));
    unsigned* bucketed = (unsigned*)bufA;     // 2*NNZ*4 = 25.6MB exact

    const int NB_SCAN = (NHT + 2047) / 2048;   // 53

    // ---- fused build ----
    part_hist_both<<<NBA, 256, 0, stream>>>(hid, hist);
    scan_blocks<<<NB_SCAN, 256, 0, stream>>>(hist, scanned, bsum, NHT);
    scan_bsums<<<1, 64, 0, stream>>>(bsum, NB_SCAN);
    scan_apply<<<(NHT + 255) / 256, 256, 0, stream>>>(scanned, bsum, NHT);
    part_scatter_both<<<NBA, 256, 0, stream>>>(hid, scanned, bucketed);
    bucket_build0<<<NBUK0, 256, 0, stream>>>(bucketed, scanned, ptr1, Binv, list1);
    bucket_build1<<<NBUK1, 256, 0, stream>>>(bucketed, scanned + NH0, ptr2, Dinv, list2, NNZ);

    // Layer 1: xW1 -> edge agg -> node agg (+b1, relu)
    gemm1_kernel<<<(N_NODES + 63) / 64, 256, 0, stream>>>(x, W1, bufA, N_NODES);
    seg_gather<0><<<(N_EDGES * 64) / 256, 256, 0, stream>>>(bufA, he, ptr1, list1, Binv, nullptr, N_EDGES, 0);
    seg_gather<1><<<(N_NODES * 64) / 256, 256, 0, stream>>>(he, bufB, ptr2, list2, Dinv, b1, N_NODES, 1);

    // Layer 2: edge agg -> node agg -> @W2 + b2 (separate epilogue kernel)
    seg_gather<2><<<(N_EDGES * 64) / 256, 256, 0, stream>>>(bufB, he, ptr1, list1, Binv, nullptr, N_EDGES, 0);
    seg_gather<3><<<(N_NODES * 64) / 256, 256, 0, stream>>>(he, bufA, ptr2, list2, Dinv, nullptr, N_NODES, 0);
    gemm2_kernel<<<(N_NODES + 3) / 4, 256, 0, stream>>>(bufA, W2, b2, out, N_NODES);
}

// Round 14
// 763.901 us; speedup vs baseline: 1.2356x; 1.2356x over previous
//
#include <hip/hip_runtime.h>
#include <hip/hip_bf16.h>

// Problem constants (match reference setup_inputs)
constexpr int N_NODES = 100000;
constexpr int N_EDGES = 20000;
constexpr int NNZ     = 3200000;
constexpr int F_IN    = 512;
constexpr int HID     = 64;
constexpr int CLS     = 70;

// CSR build via two-level counting sort, both directions fused.
constexpr int CHUNK = 32768;                         // entries per partition block
constexpr int NBA   = (NNZ + CHUNK - 1) / CHUNK;     // 98 partition blocks
constexpr int NBUK0 = (N_EDGES + 63) / 64;           // 313
constexpr int NBUK1 = (N_NODES + 127) / 128;         // 782
constexpr int NH0   = NBUK0 * NBA;                   // 30674
constexpr int NH1   = NBUK1 * NBA;                   // 76636
constexpr int NHT   = NH0 + NH1;                     // 107310 (concatenated)

// ---------------------------------------------------------------------------
// Pass A1 (fused): per-block LDS histograms for BOTH directions, one pass.
// ---------------------------------------------------------------------------
__global__ __launch_bounds__(256) void part_hist_both(const int* __restrict__ hidx,
                                                      int* __restrict__ hist) {
    __shared__ int cnt[NBUK0 + NBUK1];
    for (int b = threadIdx.x; b < NBUK0 + NBUK1; b += 256) cnt[b] = 0;
    __syncthreads();
    int base = blockIdx.x * CHUNK;
    int lim = NNZ - base; if (lim > CHUNK) lim = CHUNK;
    for (int i = threadIdx.x; i < lim; i += 256) {
        int s = hidx[base + i];
        int e = hidx[NNZ + base + i];
        atomicAdd(&cnt[e >> 6], 1);
        atomicAdd(&cnt[NBUK0 + (s >> 7)], 1);
    }
    __syncthreads();
    for (int b = threadIdx.x; b < NBUK0; b += 256)
        hist[b * NBA + blockIdx.x] = cnt[b];
    for (int b = threadIdx.x; b < NBUK1; b += 256)
        hist[NH0 + b * NBA + blockIdx.x] = cnt[NBUK0 + b];
}

// ---------------------------------------------------------------------------
// Generic exclusive scan: scan_blocks -> scan_bsums -> scan_apply
// ---------------------------------------------------------------------------
__global__ __launch_bounds__(256) void scan_blocks(const int* __restrict__ in,
                                                   int* __restrict__ out,
                                                   int* __restrict__ bsum, int n) {
    __shared__ int tmp[256];
    int base = blockIdx.x * 2048;
    int vals[8];
    int s = 0;
#pragma unroll
    for (int i = 0; i < 8; ++i) {
        int g = base + threadIdx.x * 8 + i;
        int v = (g < n) ? in[g] : 0;
        s += v;
        vals[i] = s;
    }
    tmp[threadIdx.x] = s;
    __syncthreads();
    for (int off = 1; off < 256; off <<= 1) {
        int v = 0;
        if (threadIdx.x >= off) v = tmp[threadIdx.x - off];
        __syncthreads();
        if (threadIdx.x >= off) tmp[threadIdx.x] += v;
        __syncthreads();
    }
    int prev = (threadIdx.x > 0) ? tmp[threadIdx.x - 1] : 0;
#pragma unroll
    for (int i = 0; i < 8; ++i) {
        int g = base + threadIdx.x * 8 + i;
        if (g < n) out[g + 1] = vals[i] + prev;
    }
    if (threadIdx.x == 255) bsum[blockIdx.x] = tmp[255];
}

__global__ __launch_bounds__(64) void scan_bsums(int* __restrict__ bsum, int nb) {
    int t = threadIdx.x;
    int v = (t < nb) ? bsum[t] : 0;
#pragma unroll
    for (int off = 1; off < 64; off <<= 1) {
        int u = __shfl_up(v, off);
        if (t >= off) v += u;
    }
    int ex = __shfl_up(v, 1);
    if (t == 0) ex = 0;
    if (t < nb) bsum[t] = ex;
}

__global__ __launch_bounds__(256) void scan_apply(int* __restrict__ out,
                                                  const int* __restrict__ bsum, int n) {
    int g = blockIdx.x * 256 + threadIdx.x;
    if (g >= n) return;
    out[g + 1] += bsum[g >> 11];
    if (g == 0) out[0] = 0;
}

// ---------------------------------------------------------------------------
// Pass A2 (fused): scatter BOTH packed directions in one pass over hidx.
// ---------------------------------------------------------------------------
__global__ __launch_bounds__(256) void part_scatter_both(const int* __restrict__ hidx,
                                                         const int* __restrict__ scanned,
                                                         unsigned* __restrict__ bucketed) {
    __shared__ int cur[NBUK0 + NBUK1];
    for (int b = threadIdx.x; b < NBUK0; b += 256)
        cur[b] = scanned[b * NBA + blockIdx.x];
    for (int b = threadIdx.x; b < NBUK1; b += 256)
        cur[NBUK0 + b] = scanned[NH0 + b * NBA + blockIdx.x];
    __syncthreads();
    int base = blockIdx.x * CHUNK;
    int lim = NNZ - base; if (lim > CHUNK) lim = CHUNK;
    for (int i = threadIdx.x; i < lim; i += 256) {
        int s = hidx[base + i];
        int e = hidx[NNZ + base + i];
        int pos0 = atomicAdd(&cur[e >> 6], 1);
        bucketed[pos0] = ((unsigned)e << 17) | (unsigned)s;
        int pos1 = atomicAdd(&cur[NBUK0 + (s >> 7)], 1);
        bucketed[pos1] = ((unsigned)s << 15) | (unsigned)e;
    }
}

// ---------------------------------------------------------------------------
// Pass B, dir0 with GRANULE SORT (validated R11/R12)
// ---------------------------------------------------------------------------
__global__ __launch_bounds__(256) void bucket_build0(const unsigned* __restrict__ bucketed,
                                                     const int* __restrict__ sc,
                                                     int* __restrict__ ptr_out,
                                                     float* __restrict__ inv_out,
                                                     int* __restrict__ list) {
    constexpr int NSB = 64 * 16;        // 1024 (edge_local, node>>13) keys
    __shared__ int kcnt[NSB];
    __shared__ int koff[NSB + 1];
    __shared__ int kcur[NSB];
    __shared__ int tmp[256];
    int bucket = blockIdx.x;
    int start = sc[bucket * NBA];
    int end   = sc[(bucket + 1) * NBA];
    for (int k = threadIdx.x; k < NSB; k += 256) kcnt[k] = 0;
    __syncthreads();
    for (int i = start + threadIdx.x; i < end; i += 256) {
        unsigned p = bucketed[i];
        int e_loc = (int)((p >> 17) & 63u);
        int n     = (int)(p & 0x1FFFFu);
        atomicAdd(&kcnt[e_loc * 16 + (n >> 13)], 1);
    }
    __syncthreads();
    int b4 = threadIdx.x * 4;
    int v0 = kcnt[b4], v1 = kcnt[b4 + 1], v2 = kcnt[b4 + 2], v3 = kcnt[b4 + 3];
    int s = v0 + v1 + v2 + v3;
    tmp[threadIdx.x] = s;
    __syncthreads();
    for (int off = 1; off < 256; off <<= 1) {
        int u = 0;
        if (threadIdx.x >= off) u = tmp[threadIdx.x - off];
        __syncthreads();
        if (threadIdx.x >= off) tmp[threadIdx.x] += u;
        __syncthreads();
    }
    int prev = (threadIdx.x > 0) ? tmp[threadIdx.x - 1] : 0;
    koff[b4]     = prev;
    koff[b4 + 1] = prev + v0;
    koff[b4 + 2] = prev + v0 + v1;
    koff[b4 + 3] = prev + v0 + v1 + v2;
    if (threadIdx.x == 255) koff[NSB] = tmp[255];
    __syncthreads();
    if (threadIdx.x < 64) {
        int key = bucket * 64 + threadIdx.x;
        if (key < N_EDGES) {
            int o0 = koff[threadIdx.x * 16];
            int o1 = koff[threadIdx.x * 16 + 16];
            ptr_out[key] = start + o0;
            int d = o1 - o0;
            inv_out[key] = (d > 0) ? 1.0f / (float)d : 0.0f;
        }
    }
    for (int k = threadIdx.x; k < NSB; k += 256) kcur[k] = start + koff[k];
    __syncthreads();
    for (int i = start + threadIdx.x; i < end; i += 256) {
        unsigned p = bucketed[i];
        int e_loc = (int)((p >> 17) & 63u);
        int n     = (int)(p & 0x1FFFFu);
        int pos = atomicAdd(&kcur[e_loc * 16 + (n >> 13)], 1);
        list[pos] = n;
    }
    if (bucket == NBUK0 - 1 && threadIdx.x == 0) ptr_out[N_EDGES] = NNZ;
}

// ---------------------------------------------------------------------------
// Pass B, dir1 (validated; tail folded in)
// ---------------------------------------------------------------------------
__global__ __launch_bounds__(256) void bucket_build1(const unsigned* __restrict__ bucketed,
                                                     const int* __restrict__ sc,
                                                     int* __restrict__ ptr_out,
                                                     float* __restrict__ inv_out,
                                                     int* __restrict__ list, int sub) {
    constexpr int KB = 128;
    __shared__ int kcnt[KB];
    __shared__ int koff[KB + 1];
    __shared__ int kcur[KB];
    int bucket = blockIdx.x;
    int start = sc[bucket * NBA];
    int end   = sc[(bucket + 1) * NBA];
    for (int k = threadIdx.x; k < KB; k += 256) kcnt[k] = 0;
    __syncthreads();
    for (int i = start + threadIdx.x; i < end; i += 256) {
        int kl = (int)((bucketed[i] >> 15) & (unsigned)(KB - 1));
        atomicAdd(&kcnt[kl], 1);
    }
    __syncthreads();
    if (threadIdx.x == 0) {
        int s = 0;
#pragma unroll 8
        for (int k = 0; k < KB; ++k) { koff[k] = s; s += kcnt[k]; }
        koff[KB] = s;
    }
    __syncthreads();
    if (threadIdx.x < KB) {
        int key = bucket * KB + threadIdx.x;
        int base = start + koff[threadIdx.x];
        if (key < N_NODES) {
            ptr_out[key] = base - sub;
            int d = kcnt[threadIdx.x];
            inv_out[key] = (d > 0) ? 1.0f / (float)d : 0.0f;
        }
        kcur[threadIdx.x] = base;
    }
    __syncthreads();
    for (int i = start + threadIdx.x; i < end; i += 256) {
        unsigned p = bucketed[i];
        int kl = (int)((p >> 15) & (unsigned)(KB - 1));
        int pos = atomicAdd(&kcur[kl], 1);
        list[pos - sub] = (int)(p & 0x7FFFu);
    }
    if (bucket == NBUK1 - 1 && threadIdx.x == 0) ptr_out[N_NODES] = NNZ;
}

// ---------------------------------------------------------------------------
// GEMM1: C[M][64] = A[M][512] @ B[512][64]  (fp32)  — R12 validated version
// (NO register double-buffer: R13 showed launch_bounds(256,8)'s 64-VGPR cap
// turns the prefetch registers into scratch spill: WRITE_SIZE 25->540MB,
// 3x slowdown. Keep the plain 2-barrier loop.)
// ---------------------------------------------------------------------------
__global__ __launch_bounds__(256, 8) void gemm1_kernel(const float* __restrict__ A,
                                                       const float* __restrict__ B,
                                                       float* __restrict__ C, int M) {
    constexpr int BK = 32;
    __shared__ __align__(16) float Ast[64][BK + 4];   // row-major, stride 36
    __shared__ __align__(16) float Bs[BK][HID + 4];   // k-major, stride 68
    int tid = threadIdx.x;
    int tx = tid & 15;
    int ty = tid >> 4;
    int row0 = blockIdx.x * 64;
    float acc[4][4] = {};
    int a_row = tid >> 3;
    int a_c4  = (tid & 7) * 4;
    int b_k   = tid >> 4;
    int b_c   = (tid & 15) * 4;
    for (int k0 = 0; k0 < F_IN; k0 += BK) {
#pragma unroll
        for (int l = 0; l < 2; ++l) {
            int row = a_row + 32 * l;
            int grow = row0 + row;
            float4 v = make_float4(0.f, 0.f, 0.f, 0.f);
            if (grow < M) v = *reinterpret_cast<const float4*>(&A[(size_t)grow * F_IN + k0 + a_c4]);
            *reinterpret_cast<float4*>(&Ast[row][a_c4]) = v;
        }
#pragma unroll
        for (int l = 0; l < 2; ++l) {
            int k = b_k + 16 * l;
            float4 w = *reinterpret_cast<const float4*>(&B[(size_t)(k0 + k) * HID + b_c]);
            *reinterpret_cast<float4*>(&Bs[k][b_c]) = w;
        }
        __syncthreads();
#pragma unroll
        for (int k = 0; k < BK; k += 4) {
            float4 a0 = *reinterpret_cast<const float4*>(&Ast[ty * 4 + 0][k]);
            float4 a1 = *reinterpret_cast<const float4*>(&Ast[ty * 4 + 1][k]);
            float4 a2 = *reinterpret_cast<const float4*>(&Ast[ty * 4 + 2][k]);
            float4 a3 = *reinterpret_cast<const float4*>(&Ast[ty * 4 + 3][k]);
            float4 b0 = *reinterpret_cast<const float4*>(&Bs[k + 0][tx * 4]);
            float4 b1 = *reinterpret_cast<const float4*>(&Bs[k + 1][tx * 4]);
            float4 b2 = *reinterpret_cast<const float4*>(&Bs[k + 2][tx * 4]);
            float4 b3 = *reinterpret_cast<const float4*>(&Bs[k + 3][tx * 4]);
            float a[4][4] = {{a0.x, a0.y, a0.z, a0.w},
                             {a1.x, a1.y, a1.z, a1.w},
                             {a2.x, a2.y, a2.z, a2.w},
                             {a3.x, a3.y, a3.z, a3.w}};
            float b[4][4] = {{b0.x, b0.y, b0.z, b0.w},
                             {b1.x, b1.y, b1.z, b1.w},
                             {b2.x, b2.y, b2.z, b2.w},
                             {b3.x, b3.y, b3.z, b3.w}};
#pragma unroll
            for (int s = 0; s < 4; ++s)
#pragma unroll
                for (int i = 0; i < 4; ++i)
#pragma unroll
                    for (int j = 0; j < 4; ++j)
                        acc[i][j] += a[i][s] * b[s][j];
        }
        __syncthreads();
    }
#pragma unroll
    for (int i = 0; i < 4; ++i) {
        int row = row0 + ty * 4 + i;
        if (row < M) {
            float4 v = make_float4(acc[i][0], acc[i][1], acc[i][2], acc[i][3]);
            *reinterpret_cast<float4*>(&C[(size_t)row * HID + tx * 4]) = v;
        }
    }
}

// ---------------------------------------------------------------------------
// Segment gather-sum: wave/segment, 4 groups of 16 lanes. DEPTH-4 path for
// full 64-row batches (16 loads in flight/lane) + depth-2/1 for partial
// batches; next-batch list prefetch. All shuffles uniform across 64 lanes.
// (R14: isolated vs R12 — only this kernel differs from the R12 build.)
// ---------------------------------------------------------------------------
template <int PHASE>
__global__ __launch_bounds__(256) void seg_gather(const float* __restrict__ in,
                                                  float* __restrict__ out,
                                                  const int* __restrict__ ptr,
                                                  const int* __restrict__ list,
                                                  const float* __restrict__ scale,
                                                  const float* __restrict__ bias,
                                                  int nseg, int do_relu) {
    int gid = blockIdx.x * 256 + threadIdx.x;
    int seg = gid >> 6;
    int lane = gid & 63;
    if (seg >= nseg) return;
    int beg = ptr[seg], end = ptr[seg + 1];
    int g = lane >> 4, sub = lane & 15;
    const float4* in4 = reinterpret_cast<const float4*>(in);
    float4 acc = make_float4(0.f, 0.f, 0.f, 0.f);
    int cnt0 = end - beg; if (cnt0 > 64) cnt0 = 64;
    int idx = (lane < cnt0) ? list[beg + lane] : 0;
    for (int j = beg; j < end; j += 64) {
        int cnt = end - j; if (cnt > 64) cnt = 64;        // wave-uniform
        int nj = j + 64;
        int idx_next = 0;
        if (nj < end) {
            int ncnt = end - nj; if (ncnt > 64) ncnt = 64;
            if (lane < ncnt) idx_next = list[nj + lane];
        }
        int full16 = cnt >> 4;
        int s = 0;
        for (; s + 4 <= full16; s += 4) {                 // full 64-row batch
            int r0 = 16 * s + g;
            int n[16];
            float4 v[16];
#pragma unroll
            for (int q = 0; q < 16; ++q) n[q] = __shfl(idx, r0 + 4 * q);
#pragma unroll
            for (int q = 0; q < 16; ++q) v[q] = in4[(size_t)n[q] * 16 + sub];
#pragma unroll
            for (int q = 0; q < 16; ++q) {
                acc.x += v[q].x; acc.y += v[q].y; acc.z += v[q].z; acc.w += v[q].w;
            }
        }
        for (; s + 2 <= full16; s += 2) {                 // 32 rows in flight
            int r0 = 16 * s + g;
            int n0 = __shfl(idx, r0);
            int n1 = __shfl(idx, r0 + 4);
            int n2 = __shfl(idx, r0 + 8);
            int n3 = __shfl(idx, r0 + 12);
            int n4 = __shfl(idx, r0 + 16);
            int n5 = __shfl(idx, r0 + 20);
            int n6 = __shfl(idx, r0 + 24);
            int n7 = __shfl(idx, r0 + 28);
            float4 v0 = in4[(size_t)n0 * 16 + sub];
            float4 v1 = in4[(size_t)n1 * 16 + sub];
            float4 v2 = in4[(size_t)n2 * 16 + sub];
            float4 v3 = in4[(size_t)n3 * 16 + sub];
            float4 v4 = in4[(size_t)n4 * 16 + sub];
            float4 v5 = in4[(size_t)n5 * 16 + sub];
            float4 v6 = in4[(size_t)n6 * 16 + sub];
            float4 v7 = in4[(size_t)n7 * 16 + sub];
            acc.x += (v0.x + v1.x) + (v2.x + v3.x);
            acc.y += (v0.y + v1.y) + (v2.y + v3.y);
            acc.z += (v0.z + v1.z) + (v2.z + v3.z);
            acc.w += (v0.w + v1.w) + (v2.w + v3.w);
            acc.x += (v4.x + v5.x) + (v6.x + v7.x);
            acc.y += (v4.y + v5.y) + (v6.y + v7.y);
            acc.z += (v4.z + v5.z) + (v6.z + v7.z);
            acc.w += (v4.w + v5.w) + (v6.w + v7.w);
        }
        for (; s < full16; ++s) {
            int r0 = 16 * s + g;
            int n0 = __shfl(idx, r0);
            int n1 = __shfl(idx, r0 + 4);
            int n2 = __shfl(idx, r0 + 8);
            int n3 = __shfl(idx, r0 + 12);
            float4 v0 = in4[(size_t)n0 * 16 + sub];
            float4 v1 = in4[(size_t)n1 * 16 + sub];
            float4 v2 = in4[(size_t)n2 * 16 + sub];
            float4 v3 = in4[(size_t)n3 * 16 + sub];
            acc.x += (v0.x + v1.x) + (v2.x + v3.x);
            acc.y += (v0.y + v1.y) + (v2.y + v3.y);
            acc.z += (v0.z + v1.z) + (v2.z + v3.z);
            acc.w += (v0.w + v1.w) + (v2.w + v3.w);
        }
        int rem_start = full16 << 4;
        int nrem4 = (cnt - rem_start + 3) >> 2;
        for (int t = 0; t < nrem4; ++t) {
            int row = rem_start + 4 * t + g;
            int n = __shfl(idx, row < cnt ? row : 0);
            if (row < cnt) {
                float4 v = in4[(size_t)n * 16 + sub];
                acc.x += v.x; acc.y += v.y; acc.z += v.z; acc.w += v.w;
            }
        }
        idx = idx_next;
    }
    acc.x += __shfl_xor(acc.x, 16);
    acc.y += __shfl_xor(acc.y, 16);
    acc.z += __shfl_xor(acc.z, 16);
    acc.w += __shfl_xor(acc.w, 16);
    acc.x += __shfl_xor(acc.x, 32);
    acc.y += __shfl_xor(acc.y, 32);
    acc.z += __shfl_xor(acc.z, 32);
    acc.w += __shfl_xor(acc.w, 32);
    if (lane < 16) {
        float s = scale[seg];
        acc.x *= s; acc.y *= s; acc.z *= s; acc.w *= s;
        if (bias) {
            float4 b = reinterpret_cast<const float4*>(bias)[sub];
            acc.x += b.x; acc.y += b.y; acc.z += b.z; acc.w += b.w;
        }
        if (do_relu) {
            acc.x = fmaxf(acc.x, 0.f); acc.y = fmaxf(acc.y, 0.f);
            acc.z = fmaxf(acc.z, 0.f); acc.w = fmaxf(acc.w, 0.f);
        }
        reinterpret_cast<float4*>(out)[(size_t)seg * 16 + sub] = acc;
    }
}

// ---------------------------------------------------------------------------
// GEMM2 epilogue: out[M][70] = in[M][64] @ W2[64][70] + b2  (wave per row)
// ---------------------------------------------------------------------------
__global__ __launch_bounds__(256) void gemm2_kernel(const float* __restrict__ in,
                                                    const float* __restrict__ W2,
                                                    const float* __restrict__ b2,
                                                    float* __restrict__ out, int M) {
    __shared__ float Ws[HID][72];
    __shared__ float bs[72];
    __shared__ float rows[4][HID];
    int tid = threadIdx.x;
    for (int i = tid; i < HID * 72; i += 256) {
        int r = i / 72, c = i % 72;
        Ws[r][c] = (c < CLS) ? W2[r * CLS + c] : 0.f;
    }
    if (tid < 72) bs[tid] = (tid < CLS) ? b2[tid] : 0.f;
    int wid = tid >> 6, lane = tid & 63;
    int m = blockIdx.x * 4 + wid;
    if (m < M) rows[wid][lane] = in[(size_t)m * HID + lane];
    __syncthreads();
    if (m >= M) return;
    int c2 = 64 + (lane & 7);
    float acc0 = bs[lane];
    float acc1 = bs[c2];
#pragma unroll
    for (int k = 0; k < HID; ++k) {
        float xv = rows[wid][k];
        acc0 += xv * Ws[k][lane];
        acc1 += xv * Ws[k][c2];
    }
    out[(size_t)m * CLS + lane] = acc0;
    if (lane < 6) out[(size_t)m * CLS + 64 + lane] = acc1;
}

// ---------------------------------------------------------------------------
extern "C" void kernel_launch(void* const* d_in, const int* in_sizes, int n_in,
                              void* d_out, int out_size, void* d_ws, size_t ws_size,
                              hipStream_t stream) {
    const float* x   = (const float*)d_in[0];
    const int*   hid = (const int*)d_in[1];     // [2][NNZ] int32: row0=node, row1=edge
    const float* W1  = (const float*)d_in[2];
    const float* b1  = (const float*)d_in[3];
    const float* W2  = (const float*)d_in[4];
    const float* b2  = (const float*)d_in[5];
    float* out = (float*)d_out;

    size_t off = 0;
    auto alloc = [&](size_t bytes) {
        void* p = (char*)d_ws + off;
        off += (bytes + 255) & ~(size_t)255;
        return p;
    };
    int*   ptr1  = (int*)alloc((size_t)(N_EDGES + 1) * 4);
    int*   ptr2  = (int*)alloc((size_t)(N_NODES + 1) * 4);
    int*   bsum  = (int*)alloc(64 * 4);
    float* Binv  = (float*)alloc((size_t)N_EDGES * 4);
    float* Dinv  = (float*)alloc((size_t)N_NODES * 4);
    int*   list1 = (int*)alloc((size_t)NNZ * 4);
    int*   list2 = (int*)alloc((size_t)NNZ * 4);
    float* bufA  = (float*)alloc((size_t)N_NODES * HID * 4);   // xW1, later agg2
    float* bufB  = (float*)alloc((size_t)N_NODES * HID * 4);   // h1 (relu'd)
    float* he    = (float*)alloc((size_t)N_EDGES * HID * 4);   // edge features
    (void)ws_size; (void)n_in; (void)in_sizes; (void)out_size;

    // Build-time scratch aliases (regions only written after the build):
    int*      hist     = (int*)he;
    int*      scanned  = (int*)((char*)he + (512 << 10));
    unsigned* bucketed = (unsigned*)bufA;     // 2*NNZ*4 = 25.6MB exact

    const int NB_SCAN = (NHT + 2047) / 2048;   // 53

    // ---- fused build ----
    part_hist_both<<<NBA, 256, 0, stream>>>(hid, hist);
    scan_blocks<<<NB_SCAN, 256, 0, stream>>>(hist, scanned, bsum, NHT);
    scan_bsums<<<1, 64, 0, stream>>>(bsum, NB_SCAN);
    scan_apply<<<(NHT + 255) / 256, 256, 0, stream>>>(scanned, bsum, NHT);
    part_scatter_both<<<NBA, 256, 0, stream>>>(hid, scanned, bucketed);
    bucket_build0<<<NBUK0, 256, 0, stream>>>(bucketed, scanned, ptr1, Binv, list1);
    bucket_build1<<<NBUK1, 256, 0, stream>>>(bucketed, scanned + NH0, ptr2, Dinv, list2, NNZ);

    // Layer 1: xW1 -> edge agg -> node agg (+b1, relu)
    gemm1_kernel<<<(N_NODES + 63) / 64, 256, 0, stream>>>(x, W1, bufA, N_NODES);
    seg_gather<0><<<(N_EDGES * 64) / 256, 256, 0, stream>>>(bufA, he, ptr1, list1, Binv, nullptr, N_EDGES, 0);
    seg_gather<1><<<(N_NODES * 64) / 256, 256, 0, stream>>>(he, bufB, ptr2, list2, Dinv, b1, N_NODES, 1);

    // Layer 2: edge agg -> node agg -> @W2 + b2 (separate epilogue kernel)
    seg_gather<2><<<(N_EDGES * 64) / 256, 256, 0, stream>>>(bufB, he, ptr1, list1, Binv, nullptr, N_EDGES, 0);
    seg_gather<3><<<(N_NODES * 64) / 256, 256, 0, stream>>>(he, bufA, ptr2, list2, Dinv, nullptr, N_NODES, 0);
    gemm2_kernel<<<(N_NODES + 3) / 4, 256, 0, stream>>>(bufA, W2, b2, out, N_NODES);
}

// Round 15
// 711.313 us; speedup vs baseline: 1.3269x; 1.0739x over previous
//
#include <hip/hip_runtime.h>
#include <hip/hip_bf16.h>

// Problem constants (match reference setup_inputs)
constexpr int N_NODES = 100000;
constexpr int N_EDGES = 20000;
constexpr int NNZ     = 3200000;
constexpr int F_IN    = 512;
constexpr int HID     = 64;
constexpr int CLS     = 70;

// CSR build via two-level counting sort, both directions fused.
constexpr int CHUNK = 32768;                         // entries per partition block
constexpr int NBA   = (NNZ + CHUNK - 1) / CHUNK;     // 98 partition blocks
constexpr int NBUK0 = (N_EDGES + 63) / 64;           // 313
constexpr int NBUK1 = (N_NODES + 127) / 128;         // 782
constexpr int NH0   = NBUK0 * NBA;                   // 30674
constexpr int NH1   = NBUK1 * NBA;                   // 76636
constexpr int NHT   = NH0 + NH1;                     // 107310 (concatenated)

// ---------------------------------------------------------------------------
// Pass A1 (fused): per-block LDS histograms for BOTH directions, one pass.
// ---------------------------------------------------------------------------
__global__ __launch_bounds__(256) void part_hist_both(const int* __restrict__ hidx,
                                                      int* __restrict__ hist) {
    __shared__ int cnt[NBUK0 + NBUK1];
    for (int b = threadIdx.x; b < NBUK0 + NBUK1; b += 256) cnt[b] = 0;
    __syncthreads();
    int base = blockIdx.x * CHUNK;
    int lim = NNZ - base; if (lim > CHUNK) lim = CHUNK;
    for (int i = threadIdx.x; i < lim; i += 256) {
        int s = hidx[base + i];
        int e = hidx[NNZ + base + i];
        atomicAdd(&cnt[e >> 6], 1);
        atomicAdd(&cnt[NBUK0 + (s >> 7)], 1);
    }
    __syncthreads();
    for (int b = threadIdx.x; b < NBUK0; b += 256)
        hist[b * NBA + blockIdx.x] = cnt[b];
    for (int b = threadIdx.x; b < NBUK1; b += 256)
        hist[NH0 + b * NBA + blockIdx.x] = cnt[NBUK0 + b];
}

// ---------------------------------------------------------------------------
// Generic exclusive scan: scan_blocks -> scan_bsums -> scan_apply
// ---------------------------------------------------------------------------
__global__ __launch_bounds__(256) void scan_blocks(const int* __restrict__ in,
                                                   int* __restrict__ out,
                                                   int* __restrict__ bsum, int n) {
    __shared__ int tmp[256];
    int base = blockIdx.x * 2048;
    int vals[8];
    int s = 0;
#pragma unroll
    for (int i = 0; i < 8; ++i) {
        int g = base + threadIdx.x * 8 + i;
        int v = (g < n) ? in[g] : 0;
        s += v;
        vals[i] = s;
    }
    tmp[threadIdx.x] = s;
    __syncthreads();
    for (int off = 1; off < 256; off <<= 1) {
        int v = 0;
        if (threadIdx.x >= off) v = tmp[threadIdx.x - off];
        __syncthreads();
        if (threadIdx.x >= off) tmp[threadIdx.x] += v;
        __syncthreads();
    }
    int prev = (threadIdx.x > 0) ? tmp[threadIdx.x - 1] : 0;
#pragma unroll
    for (int i = 0; i < 8; ++i) {
        int g = base + threadIdx.x * 8 + i;
        if (g < n) out[g + 1] = vals[i] + prev;
    }
    if (threadIdx.x == 255) bsum[blockIdx.x] = tmp[255];
}

__global__ __launch_bounds__(64) void scan_bsums(int* __restrict__ bsum, int nb) {
    int t = threadIdx.x;
    int v = (t < nb) ? bsum[t] : 0;
#pragma unroll
    for (int off = 1; off < 64; off <<= 1) {
        int u = __shfl_up(v, off);
        if (t >= off) v += u;
    }
    int ex = __shfl_up(v, 1);
    if (t == 0) ex = 0;
    if (t < nb) bsum[t] = ex;
}

__global__ __launch_bounds__(256) void scan_apply(int* __restrict__ out,
                                                  const int* __restrict__ bsum, int n) {
    int g = blockIdx.x * 256 + threadIdx.x;
    if (g >= n) return;
    out[g + 1] += bsum[g >> 11];
    if (g == 0) out[0] = 0;
}

// ---------------------------------------------------------------------------
// Pass A2 (fused): scatter BOTH packed directions in one pass over hidx.
// ---------------------------------------------------------------------------
__global__ __launch_bounds__(256) void part_scatter_both(const int* __restrict__ hidx,
                                                         const int* __restrict__ scanned,
                                                         unsigned* __restrict__ bucketed) {
    __shared__ int cur[NBUK0 + NBUK1];
    for (int b = threadIdx.x; b < NBUK0; b += 256)
        cur[b] = scanned[b * NBA + blockIdx.x];
    for (int b = threadIdx.x; b < NBUK1; b += 256)
        cur[NBUK0 + b] = scanned[NH0 + b * NBA + blockIdx.x];
    __syncthreads();
    int base = blockIdx.x * CHUNK;
    int lim = NNZ - base; if (lim > CHUNK) lim = CHUNK;
    for (int i = threadIdx.x; i < lim; i += 256) {
        int s = hidx[base + i];
        int e = hidx[NNZ + base + i];
        int pos0 = atomicAdd(&cur[e >> 6], 1);
        bucketed[pos0] = ((unsigned)e << 17) | (unsigned)s;
        int pos1 = atomicAdd(&cur[NBUK0 + (s >> 7)], 1);
        bucketed[pos1] = ((unsigned)s << 15) | (unsigned)e;
    }
}

// ---------------------------------------------------------------------------
// Pass B, dir0 with GRANULE SORT (validated R11/R12)
// ---------------------------------------------------------------------------
__global__ __launch_bounds__(256) void bucket_build0(const unsigned* __restrict__ bucketed,
                                                     const int* __restrict__ sc,
                                                     int* __restrict__ ptr_out,
                                                     float* __restrict__ inv_out,
                                                     int* __restrict__ list) {
    constexpr int NSB = 64 * 16;        // 1024 (edge_local, node>>13) keys
    __shared__ int kcnt[NSB];
    __shared__ int koff[NSB + 1];
    __shared__ int kcur[NSB];
    __shared__ int tmp[256];
    int bucket = blockIdx.x;
    int start = sc[bucket * NBA];
    int end   = sc[(bucket + 1) * NBA];
    for (int k = threadIdx.x; k < NSB; k += 256) kcnt[k] = 0;
    __syncthreads();
    for (int i = start + threadIdx.x; i < end; i += 256) {
        unsigned p = bucketed[i];
        int e_loc = (int)((p >> 17) & 63u);
        int n     = (int)(p & 0x1FFFFu);
        atomicAdd(&kcnt[e_loc * 16 + (n >> 13)], 1);
    }
    __syncthreads();
    int b4 = threadIdx.x * 4;
    int v0 = kcnt[b4], v1 = kcnt[b4 + 1], v2 = kcnt[b4 + 2], v3 = kcnt[b4 + 3];
    int s = v0 + v1 + v2 + v3;
    tmp[threadIdx.x] = s;
    __syncthreads();
    for (int off = 1; off < 256; off <<= 1) {
        int u = 0;
        if (threadIdx.x >= off) u = tmp[threadIdx.x - off];
        __syncthreads();
        if (threadIdx.x >= off) tmp[threadIdx.x] += u;
        __syncthreads();
    }
    int prev = (threadIdx.x > 0) ? tmp[threadIdx.x - 1] : 0;
    koff[b4]     = prev;
    koff[b4 + 1] = prev + v0;
    koff[b4 + 2] = prev + v0 + v1;
    koff[b4 + 3] = prev + v0 + v1 + v2;
    if (threadIdx.x == 255) koff[NSB] = tmp[255];
    __syncthreads();
    if (threadIdx.x < 64) {
        int key = bucket * 64 + threadIdx.x;
        if (key < N_EDGES) {
            int o0 = koff[threadIdx.x * 16];
            int o1 = koff[threadIdx.x * 16 + 16];
            ptr_out[key] = start + o0;
            int d = o1 - o0;
            inv_out[key] = (d > 0) ? 1.0f / (float)d : 0.0f;
        }
    }
    for (int k = threadIdx.x; k < NSB; k += 256) kcur[k] = start + koff[k];
    __syncthreads();
    for (int i = start + threadIdx.x; i < end; i += 256) {
        unsigned p = bucketed[i];
        int e_loc = (int)((p >> 17) & 63u);
        int n     = (int)(p & 0x1FFFFu);
        int pos = atomicAdd(&kcur[e_loc * 16 + (n >> 13)], 1);
        list[pos] = n;
    }
    if (bucket == NBUK0 - 1 && threadIdx.x == 0) ptr_out[N_EDGES] = NNZ;
}

// ---------------------------------------------------------------------------
// Pass B, dir1 (validated; tail folded in)
// ---------------------------------------------------------------------------
__global__ __launch_bounds__(256) void bucket_build1(const unsigned* __restrict__ bucketed,
                                                     const int* __restrict__ sc,
                                                     int* __restrict__ ptr_out,
                                                     float* __restrict__ inv_out,
                                                     int* __restrict__ list, int sub) {
    constexpr int KB = 128;
    __shared__ int kcnt[KB];
    __shared__ int koff[KB + 1];
    __shared__ int kcur[KB];
    int bucket = blockIdx.x;
    int start = sc[bucket * NBA];
    int end   = sc[(bucket + 1) * NBA];
    for (int k = threadIdx.x; k < KB; k += 256) kcnt[k] = 0;
    __syncthreads();
    for (int i = start + threadIdx.x; i < end; i += 256) {
        int kl = (int)((bucketed[i] >> 15) & (unsigned)(KB - 1));
        atomicAdd(&kcnt[kl], 1);
    }
    __syncthreads();
    if (threadIdx.x == 0) {
        int s = 0;
#pragma unroll 8
        for (int k = 0; k < KB; ++k) { koff[k] = s; s += kcnt[k]; }
        koff[KB] = s;
    }
    __syncthreads();
    if (threadIdx.x < KB) {
        int key = bucket * KB + threadIdx.x;
        int base = start + koff[threadIdx.x];
        if (key < N_NODES) {
            ptr_out[key] = base - sub;
            int d = kcnt[threadIdx.x];
            inv_out[key] = (d > 0) ? 1.0f / (float)d : 0.0f;
        }
        kcur[threadIdx.x] = base;
    }
    __syncthreads();
    for (int i = start + threadIdx.x; i < end; i += 256) {
        unsigned p = bucketed[i];
        int kl = (int)((p >> 15) & (unsigned)(KB - 1));
        int pos = atomicAdd(&kcur[kl], 1);
        list[pos - sub] = (int)(p & 0x7FFFu);
    }
    if (bucket == NBUK1 - 1 && threadIdx.x == 0) ptr_out[N_NODES] = NNZ;
}

// ---------------------------------------------------------------------------
// GEMM1: C[M][64] = A[M][512] @ B[512][64]  (fp32)  — R12 validated version.
// BM=64, BK=32, 17.9KB LDS -> 8 blocks/CU. No reg double-buffer (R13 lesson:
// launch_bounds(256,8)'s 64-VGPR cap turns prefetch regs into scratch spill).
// ---------------------------------------------------------------------------
__global__ __launch_bounds__(256, 8) void gemm1_kernel(const float* __restrict__ A,
                                                       const float* __restrict__ B,
                                                       float* __restrict__ C, int M) {
    constexpr int BK = 32;
    __shared__ __align__(16) float Ast[64][BK + 4];   // row-major, stride 36
    __shared__ __align__(16) float Bs[BK][HID + 4];   // k-major, stride 68
    int tid = threadIdx.x;
    int tx = tid & 15;
    int ty = tid >> 4;
    int row0 = blockIdx.x * 64;
    float acc[4][4] = {};
    int a_row = tid >> 3;
    int a_c4  = (tid & 7) * 4;
    int b_k   = tid >> 4;
    int b_c   = (tid & 15) * 4;
    for (int k0 = 0; k0 < F_IN; k0 += BK) {
#pragma unroll
        for (int l = 0; l < 2; ++l) {
            int row = a_row + 32 * l;
            int grow = row0 + row;
            float4 v = make_float4(0.f, 0.f, 0.f, 0.f);
            if (grow < M) v = *reinterpret_cast<const float4*>(&A[(size_t)grow * F_IN + k0 + a_c4]);
            *reinterpret_cast<float4*>(&Ast[row][a_c4]) = v;
        }
#pragma unroll
        for (int l = 0; l < 2; ++l) {
            int k = b_k + 16 * l;
            float4 w = *reinterpret_cast<const float4*>(&B[(size_t)(k0 + k) * HID + b_c]);
            *reinterpret_cast<float4*>(&Bs[k][b_c]) = w;
        }
        __syncthreads();
#pragma unroll
        for (int k = 0; k < BK; k += 4) {
            float4 a0 = *reinterpret_cast<const float4*>(&Ast[ty * 4 + 0][k]);
            float4 a1 = *reinterpret_cast<const float4*>(&Ast[ty * 4 + 1][k]);
            float4 a2 = *reinterpret_cast<const float4*>(&Ast[ty * 4 + 2][k]);
            float4 a3 = *reinterpret_cast<const float4*>(&Ast[ty * 4 + 3][k]);
            float4 b0 = *reinterpret_cast<const float4*>(&Bs[k + 0][tx * 4]);
            float4 b1 = *reinterpret_cast<const float4*>(&Bs[k + 1][tx * 4]);
            float4 b2 = *reinterpret_cast<const float4*>(&Bs[k + 2][tx * 4]);
            float4 b3 = *reinterpret_cast<const float4*>(&Bs[k + 3][tx * 4]);
            float a[4][4] = {{a0.x, a0.y, a0.z, a0.w},
                             {a1.x, a1.y, a1.z, a1.w},
                             {a2.x, a2.y, a2.z, a2.w},
                             {a3.x, a3.y, a3.z, a3.w}};
            float b[4][4] = {{b0.x, b0.y, b0.z, b0.w},
                             {b1.x, b1.y, b1.z, b1.w},
                             {b2.x, b2.y, b2.z, b2.w},
                             {b3.x, b3.y, b3.z, b3.w}};
#pragma unroll
            for (int s = 0; s < 4; ++s)
#pragma unroll
                for (int i = 0; i < 4; ++i)
#pragma unroll
                    for (int j = 0; j < 4; ++j)
                        acc[i][j] += a[i][s] * b[s][j];
        }
        __syncthreads();
    }
#pragma unroll
    for (int i = 0; i < 4; ++i) {
        int row = row0 + ty * 4 + i;
        if (row < M) {
            float4 v = make_float4(acc[i][0], acc[i][1], acc[i][2], acc[i][3]);
            *reinterpret_cast<float4*>(&C[(size_t)row * HID + tx * 4]) = v;
        }
    }
}

// ---------------------------------------------------------------------------
// Segment gather-sum (R12 validated): wave/segment, 4 groups of 16 lanes,
// depth-2 unroll = 32 rows in flight (R14 showed depth-4 + prefetch costs
// +51us via VGPR pressure). All shuffles uniform across 64 lanes.
// ---------------------------------------------------------------------------
template <int PHASE>
__global__ __launch_bounds__(256) void seg_gather(const float* __restrict__ in,
                                                  float* __restrict__ out,
                                                  const int* __restrict__ ptr,
                                                  const int* __restrict__ list,
                                                  const float* __restrict__ scale,
                                                  const float* __restrict__ bias,
                                                  int nseg, int do_relu) {
    int gid = blockIdx.x * 256 + threadIdx.x;
    int seg = gid >> 6;
    int lane = gid & 63;
    if (seg >= nseg) return;
    int beg = ptr[seg], end = ptr[seg + 1];
    int g = lane >> 4, sub = lane & 15;
    const float4* in4 = reinterpret_cast<const float4*>(in);
    float4 acc = make_float4(0.f, 0.f, 0.f, 0.f);
    for (int j = beg; j < end; j += 64) {
        int cnt = end - j; if (cnt > 64) cnt = 64;
        int idx = (lane < cnt) ? list[j + lane] : 0;
        int full16 = cnt >> 4;
        int s = 0;
        for (; s + 2 <= full16; s += 2) {
            int r0 = 16 * s + g;
            int n0 = __shfl(idx, r0);
            int n1 = __shfl(idx, r0 + 4);
            int n2 = __shfl(idx, r0 + 8);
            int n3 = __shfl(idx, r0 + 12);
            int n4 = __shfl(idx, r0 + 16);
            int n5 = __shfl(idx, r0 + 20);
            int n6 = __shfl(idx, r0 + 24);
            int n7 = __shfl(idx, r0 + 28);
            float4 v0 = in4[(size_t)n0 * 16 + sub];
            float4 v1 = in4[(size_t)n1 * 16 + sub];
            float4 v2 = in4[(size_t)n2 * 16 + sub];
            float4 v3 = in4[(size_t)n3 * 16 + sub];
            float4 v4 = in4[(size_t)n4 * 16 + sub];
            float4 v5 = in4[(size_t)n5 * 16 + sub];
            float4 v6 = in4[(size_t)n6 * 16 + sub];
            float4 v7 = in4[(size_t)n7 * 16 + sub];
            acc.x += (v0.x + v1.x) + (v2.x + v3.x);
            acc.y += (v0.y + v1.y) + (v2.y + v3.y);
            acc.z += (v0.z + v1.z) + (v2.z + v3.z);
            acc.w += (v0.w + v1.w) + (v2.w + v3.w);
            acc.x += (v4.x + v5.x) + (v6.x + v7.x);
            acc.y += (v4.y + v5.y) + (v6.y + v7.y);
            acc.z += (v4.z + v5.z) + (v6.z + v7.z);
            acc.w += (v4.w + v5.w) + (v6.w + v7.w);
        }
        for (; s < full16; ++s) {
            int r0 = 16 * s + g;
            int n0 = __shfl(idx, r0);
            int n1 = __shfl(idx, r0 + 4);
            int n2 = __shfl(idx, r0 + 8);
            int n3 = __shfl(idx, r0 + 12);
            float4 v0 = in4[(size_t)n0 * 16 + sub];
            float4 v1 = in4[(size_t)n1 * 16 + sub];
            float4 v2 = in4[(size_t)n2 * 16 + sub];
            float4 v3 = in4[(size_t)n3 * 16 + sub];
            acc.x += (v0.x + v1.x) + (v2.x + v3.x);
            acc.y += (v0.y + v1.y) + (v2.y + v3.y);
            acc.z += (v0.z + v1.z) + (v2.z + v3.z);
            acc.w += (v0.w + v1.w) + (v2.w + v3.w);
        }
        int rem_start = full16 << 4;
        int nrem4 = (cnt - rem_start + 3) >> 2;
        for (int t = 0; t < nrem4; ++t) {
            int row = rem_start + 4 * t + g;
            int n = __shfl(idx, row < cnt ? row : 0);
            if (row < cnt) {
                float4 v = in4[(size_t)n * 16 + sub];
                acc.x += v.x; acc.y += v.y; acc.z += v.z; acc.w += v.w;
            }
        }
    }
    acc.x += __shfl_xor(acc.x, 16);
    acc.y += __shfl_xor(acc.y, 16);
    acc.z += __shfl_xor(acc.z, 16);
    acc.w += __shfl_xor(acc.w, 16);
    acc.x += __shfl_xor(acc.x, 32);
    acc.y += __shfl_xor(acc.y, 32);
    acc.z += __shfl_xor(acc.z, 32);
    acc.w += __shfl_xor(acc.w, 32);
    if (lane < 16) {
        float s = scale[seg];
        acc.x *= s; acc.y *= s; acc.z *= s; acc.w *= s;
        if (bias) {
            float4 b = reinterpret_cast<const float4*>(bias)[sub];
            acc.x += b.x; acc.y += b.y; acc.z += b.z; acc.w += b.w;
        }
        if (do_relu) {
            acc.x = fmaxf(acc.x, 0.f); acc.y = fmaxf(acc.y, 0.f);
            acc.z = fmaxf(acc.z, 0.f); acc.w = fmaxf(acc.w, 0.f);
        }
        reinterpret_cast<float4*>(out)[(size_t)seg * 16 + sub] = acc;
    }
}

// ---------------------------------------------------------------------------
// GEMM2 epilogue: out[M][70] = in[M][64] @ W2[64][70] + b2  (wave per row)
// (kept separate — R11 showed fusion into phase 3 regresses)
// ---------------------------------------------------------------------------
__global__ __launch_bounds__(256) void gemm2_kernel(const float* __restrict__ in,
                                                    const float* __restrict__ W2,
                                                    const float* __restrict__ b2,
                                                    float* __restrict__ out, int M) {
    __shared__ float Ws[HID][72];
    __shared__ float bs[72];
    __shared__ float rows[4][HID];
    int tid = threadIdx.x;
    for (int i = tid; i < HID * 72; i += 256) {
        int r = i / 72, c = i % 72;
        Ws[r][c] = (c < CLS) ? W2[r * CLS + c] : 0.f;
    }
    if (tid < 72) bs[tid] = (tid < CLS) ? b2[tid] : 0.f;
    int wid = tid >> 6, lane = tid & 63;
    int m = blockIdx.x * 4 + wid;
    if (m < M) rows[wid][lane] = in[(size_t)m * HID + lane];
    __syncthreads();
    if (m >= M) return;
    int c2 = 64 + (lane & 7);
    float acc0 = bs[lane];
    float acc1 = bs[c2];
#pragma unroll
    for (int k = 0; k < HID; ++k) {
        float xv = rows[wid][k];
        acc0 += xv * Ws[k][lane];
        acc1 += xv * Ws[k][c2];
    }
    out[(size_t)m * CLS + lane] = acc0;
    if (lane < 6) out[(size_t)m * CLS + 64 + lane] = acc1;
}

// ---------------------------------------------------------------------------
extern "C" void kernel_launch(void* const* d_in, const int* in_sizes, int n_in,
                              void* d_out, int out_size, void* d_ws, size_t ws_size,
                              hipStream_t stream) {
    const float* x   = (const float*)d_in[0];
    const int*   hid = (const int*)d_in[1];     // [2][NNZ] int32: row0=node, row1=edge
    const float* W1  = (const float*)d_in[2];
    const float* b1  = (const float*)d_in[3];
    const float* W2  = (const float*)d_in[4];
    const float* b2  = (const float*)d_in[5];
    float* out = (float*)d_out;

    size_t off = 0;
    auto alloc = [&](size_t bytes) {
        void* p = (char*)d_ws + off;
        off += (bytes + 255) & ~(size_t)255;
        return p;
    };
    int*   ptr1  = (int*)alloc((size_t)(N_EDGES + 1) * 4);
    int*   ptr2  = (int*)alloc((size_t)(N_NODES + 1) * 4);
    int*   bsum  = (int*)alloc(64 * 4);
    float* Binv  = (float*)alloc((size_t)N_EDGES * 4);
    float* Dinv  = (float*)alloc((size_t)N_NODES * 4);
    int*   list1 = (int*)alloc((size_t)NNZ * 4);
    int*   list2 = (int*)alloc((size_t)NNZ * 4);
    float* bufA  = (float*)alloc((size_t)N_NODES * HID * 4);   // xW1, later agg2
    float* bufB  = (float*)alloc((size_t)N_NODES * HID * 4);   // h1 (relu'd)
    float* he    = (float*)alloc((size_t)N_EDGES * HID * 4);   // edge features
    (void)ws_size; (void)n_in; (void)in_sizes; (void)out_size;

    // Build-time scratch aliases (regions only written after the build):
    int*      hist     = (int*)he;
    int*      scanned  = (int*)((char*)he + (512 << 10));
    unsigned* bucketed = (unsigned*)bufA;     // 2*NNZ*4 = 25.6MB exact

    const int NB_SCAN = (NHT + 2047) / 2048;   // 53

    // ---- fused build ----
    part_hist_both<<<NBA, 256, 0, stream>>>(hid, hist);
    scan_blocks<<<NB_SCAN, 256, 0, stream>>>(hist, scanned, bsum, NHT);
    scan_bsums<<<1, 64, 0, stream>>>(bsum, NB_SCAN);
    scan_apply<<<(NHT + 255) / 256, 256, 0, stream>>>(scanned, bsum, NHT);
    part_scatter_both<<<NBA, 256, 0, stream>>>(hid, scanned, bucketed);
    bucket_build0<<<NBUK0, 256, 0, stream>>>(bucketed, scanned, ptr1, Binv, list1);
    bucket_build1<<<NBUK1, 256, 0, stream>>>(bucketed, scanned + NH0, ptr2, Dinv, list2, NNZ);

    // Layer 1: xW1 -> edge agg -> node agg (+b1, relu)
    gemm1_kernel<<<(N_NODES + 63) / 64, 256, 0, stream>>>(x, W1, bufA, N_NODES);
    seg_gather<0><<<(N_EDGES * 64) / 256, 256, 0, stream>>>(bufA, he, ptr1, list1, Binv, nullptr, N_EDGES, 0);
    seg_gather<1><<<(N_NODES * 64) / 256, 256, 0, stream>>>(he, bufB, ptr2, list2, Dinv, b1, N_NODES, 1);

    // Layer 2: edge agg -> node agg -> @W2 + b2 (separate epilogue kernel)
    seg_gather<2><<<(N_EDGES * 64) / 256, 256, 0, stream>>>(bufB, he, ptr1, list1, Binv, nullptr, N_EDGES, 0);
    seg_gather<3><<<(N_NODES * 64) / 256, 256, 0, stream>>>(he, bufA, ptr2, list2, Dinv, nullptr, N_NODES, 0);
    gemm2_kernel<<<(N_NODES + 3) / 4, 256, 0, stream>>>(bufA, W2, b2, out, N_NODES);
}

// Round 16
// 687.870 us; speedup vs baseline: 1.3721x; 1.0341x over previous
//
#include <hip/hip_runtime.h>
#include <hip/hip_bf16.h>

// Problem constants (match reference setup_inputs)
constexpr int N_NODES = 100000;
constexpr int N_EDGES = 20000;
constexpr int NNZ     = 3200000;
constexpr int F_IN    = 512;
constexpr int HID     = 64;
constexpr int CLS     = 70;

// CSR build via two-level counting sort, both directions fused.
constexpr int CHUNK = 32768;                         // entries per partition block
constexpr int NBA   = (NNZ + CHUNK - 1) / CHUNK;     // 98 partition blocks
constexpr int NBUK0 = (N_EDGES + 63) / 64;           // 313
constexpr int NBUK1 = (N_NODES + 127) / 128;         // 782
constexpr int NH0   = NBUK0 * NBA;                   // 30674
constexpr int NH1   = NBUK1 * NBA;                   // 76636
constexpr int NHT   = NH0 + NH1;                     // 107310 (concatenated)
constexpr int G1_BLOCKS = (N_NODES + 63) / 64;       // 1563 gemm1 row-blocks

// ---------------------------------------------------------------------------
// Pass A1 (fused): per-block LDS histograms for BOTH directions, one pass.
// ---------------------------------------------------------------------------
__global__ __launch_bounds__(256) void part_hist_both(const int* __restrict__ hidx,
                                                      int* __restrict__ hist) {
    __shared__ int cnt[NBUK0 + NBUK1];
    for (int b = threadIdx.x; b < NBUK0 + NBUK1; b += 256) cnt[b] = 0;
    __syncthreads();
    int base = blockIdx.x * CHUNK;
    int lim = NNZ - base; if (lim > CHUNK) lim = CHUNK;
    for (int i = threadIdx.x; i < lim; i += 256) {
        int s = hidx[base + i];
        int e = hidx[NNZ + base + i];
        atomicAdd(&cnt[e >> 6], 1);
        atomicAdd(&cnt[NBUK0 + (s >> 7)], 1);
    }
    __syncthreads();
    for (int b = threadIdx.x; b < NBUK0; b += 256)
        hist[b * NBA + blockIdx.x] = cnt[b];
    for (int b = threadIdx.x; b < NBUK1; b += 256)
        hist[NH0 + b * NBA + blockIdx.x] = cnt[NBUK0 + b];
}

// ---------------------------------------------------------------------------
// Generic exclusive scan: scan_blocks -> scan_bsums -> scan_apply
// ---------------------------------------------------------------------------
__global__ __launch_bounds__(256) void scan_blocks(const int* __restrict__ in,
                                                   int* __restrict__ out,
                                                   int* __restrict__ bsum, int n) {
    __shared__ int tmp[256];
    int base = blockIdx.x * 2048;
    int vals[8];
    int s = 0;
#pragma unroll
    for (int i = 0; i < 8; ++i) {
        int g = base + threadIdx.x * 8 + i;
        int v = (g < n) ? in[g] : 0;
        s += v;
        vals[i] = s;
    }
    tmp[threadIdx.x] = s;
    __syncthreads();
    for (int off = 1; off < 256; off <<= 1) {
        int v = 0;
        if (threadIdx.x >= off) v = tmp[threadIdx.x - off];
        __syncthreads();
        if (threadIdx.x >= off) tmp[threadIdx.x] += v;
        __syncthreads();
    }
    int prev = (threadIdx.x > 0) ? tmp[threadIdx.x - 1] : 0;
#pragma unroll
    for (int i = 0; i < 8; ++i) {
        int g = base + threadIdx.x * 8 + i;
        if (g < n) out[g + 1] = vals[i] + prev;
    }
    if (threadIdx.x == 255) bsum[blockIdx.x] = tmp[255];
}

__global__ __launch_bounds__(64) void scan_bsums(int* __restrict__ bsum, int nb) {
    int t = threadIdx.x;
    int v = (t < nb) ? bsum[t] : 0;
#pragma unroll
    for (int off = 1; off < 64; off <<= 1) {
        int u = __shfl_up(v, off);
        if (t >= off) v += u;
    }
    int ex = __shfl_up(v, 1);
    if (t == 0) ex = 0;
    if (t < nb) bsum[t] = ex;
}

__global__ __launch_bounds__(256) void scan_apply(int* __restrict__ out,
                                                  const int* __restrict__ bsum, int n) {
    int g = blockIdx.x * 256 + threadIdx.x;
    if (g >= n) return;
    out[g + 1] += bsum[g >> 11];
    if (g == 0) out[0] = 0;
}

// ---------------------------------------------------------------------------
// Pass A2 (fused): scatter BOTH packed directions in one pass over hidx.
// ---------------------------------------------------------------------------
__global__ __launch_bounds__(256) void part_scatter_both(const int* __restrict__ hidx,
                                                         const int* __restrict__ scanned,
                                                         unsigned* __restrict__ bucketed) {
    __shared__ int cur[NBUK0 + NBUK1];
    for (int b = threadIdx.x; b < NBUK0; b += 256)
        cur[b] = scanned[b * NBA + blockIdx.x];
    for (int b = threadIdx.x; b < NBUK1; b += 256)
        cur[NBUK0 + b] = scanned[NH0 + b * NBA + blockIdx.x];
    __syncthreads();
    int base = blockIdx.x * CHUNK;
    int lim = NNZ - base; if (lim > CHUNK) lim = CHUNK;
    for (int i = threadIdx.x; i < lim; i += 256) {
        int s = hidx[base + i];
        int e = hidx[NNZ + base + i];
        int pos0 = atomicAdd(&cur[e >> 6], 1);
        bucketed[pos0] = ((unsigned)e << 17) | (unsigned)s;
        int pos1 = atomicAdd(&cur[NBUK0 + (s >> 7)], 1);
        bucketed[pos1] = ((unsigned)s << 15) | (unsigned)e;
    }
}

// ---------------------------------------------------------------------------
// FUSED independent-task kernel: blocks [0,313) run bucket_build0 (granule
// sort), [313,1095) run bucket_build1, [1095,2658) run gemm1. The three
// tasks are mutually independent (bb* read bucketed=bufB and write CSR
// arrays; gemm1 reads x/W1 and writes bufA) so co-scheduling hides the
// entire bucket-build stage (~70us) under gemm1 (~105us). Unlike R11's
// regression there is NO intra-block coupling: each block executes exactly
// one validated code path. LDS is a 17920B union (= gemm1's footprint;
// bb0 needs 13316B) so gemm1 keeps 8 blocks/CU.
// ---------------------------------------------------------------------------
__global__ __launch_bounds__(256, 8) void build_gemm_fused(
        const unsigned* __restrict__ bucketed,
        const int* __restrict__ scanned,
        int* __restrict__ ptr1, float* __restrict__ Binv, int* __restrict__ list1,
        int* __restrict__ ptr2, float* __restrict__ Dinv, int* __restrict__ list2,
        const float* __restrict__ A, const float* __restrict__ Bw,
        float* __restrict__ C, int M) {
    __shared__ __align__(16) char smem[17920];
    int bid = blockIdx.x;
    int tid = threadIdx.x;
    if (bid < NBUK0) {
        // ---- bucket_build0: 64 edges x 16 node-granules (node>>13) ----
        int* kcnt = (int*)smem;            // 1024
        int* koff = kcnt + 1024;           // 1025
        int* kcur = koff + 1025;           // 1024
        int* tmp  = kcur + 1024;           // 256   (13316B total)
        constexpr int NSB = 64 * 16;
        int bucket = bid;
        int start = scanned[bucket * NBA];
        int end   = scanned[(bucket + 1) * NBA];
        for (int k = tid; k < NSB; k += 256) kcnt[k] = 0;
        __syncthreads();
        for (int i = start + tid; i < end; i += 256) {
            unsigned p = bucketed[i];
            int e_loc = (int)((p >> 17) & 63u);
            int n     = (int)(p & 0x1FFFFu);
            atomicAdd(&kcnt[e_loc * 16 + (n >> 13)], 1);
        }
        __syncthreads();
        int b4 = tid * 4;
        int v0 = kcnt[b4], v1 = kcnt[b4 + 1], v2 = kcnt[b4 + 2], v3 = kcnt[b4 + 3];
        int s = v0 + v1 + v2 + v3;
        tmp[tid] = s;
        __syncthreads();
        for (int off = 1; off < 256; off <<= 1) {
            int u = 0;
            if (tid >= off) u = tmp[tid - off];
            __syncthreads();
            if (tid >= off) tmp[tid] += u;
            __syncthreads();
        }
        int prev = (tid > 0) ? tmp[tid - 1] : 0;
        koff[b4]     = prev;
        koff[b4 + 1] = prev + v0;
        koff[b4 + 2] = prev + v0 + v1;
        koff[b4 + 3] = prev + v0 + v1 + v2;
        if (tid == 255) koff[NSB] = tmp[255];
        __syncthreads();
        if (tid < 64) {
            int key = bucket * 64 + tid;
            if (key < N_EDGES) {
                int o0 = koff[tid * 16];
                int o1 = koff[tid * 16 + 16];
                ptr1[key] = start + o0;
                int d = o1 - o0;
                Binv[key] = (d > 0) ? 1.0f / (float)d : 0.0f;
            }
        }
        for (int k = tid; k < NSB; k += 256) kcur[k] = start + koff[k];
        __syncthreads();
        for (int i = start + tid; i < end; i += 256) {
            unsigned p = bucketed[i];
            int e_loc = (int)((p >> 17) & 63u);
            int n     = (int)(p & 0x1FFFFu);
            int pos = atomicAdd(&kcur[e_loc * 16 + (n >> 13)], 1);
            list1[pos] = n;
        }
        if (bucket == NBUK0 - 1 && tid == 0) ptr1[N_EDGES] = NNZ;
    } else if (bid < NBUK0 + NBUK1) {
        // ---- bucket_build1 ----
        constexpr int KB = 128;
        int* kcnt = (int*)smem;            // 128
        int* koff = kcnt + 128;            // 129
        int* kcur = koff + 129;            // 128
        const int* sc = scanned + NH0;
        int bucket = bid - NBUK0;
        int sub = NNZ;
        int start = sc[bucket * NBA];
        int end   = sc[(bucket + 1) * NBA];
        for (int k = tid; k < KB; k += 256) kcnt[k] = 0;
        __syncthreads();
        for (int i = start + tid; i < end; i += 256) {
            int kl = (int)((bucketed[i] >> 15) & (unsigned)(KB - 1));
            atomicAdd(&kcnt[kl], 1);
        }
        __syncthreads();
        if (tid == 0) {
            int s = 0;
#pragma unroll 8
            for (int k = 0; k < KB; ++k) { koff[k] = s; s += kcnt[k]; }
            koff[KB] = s;
        }
        __syncthreads();
        if (tid < KB) {
            int key = bucket * KB + tid;
            int base = start + koff[tid];
            if (key < N_NODES) {
                ptr2[key] = base - sub;
                int d = kcnt[tid];
                Dinv[key] = (d > 0) ? 1.0f / (float)d : 0.0f;
            }
            kcur[tid] = base;
        }
        __syncthreads();
        for (int i = start + tid; i < end; i += 256) {
            unsigned p = bucketed[i];
            int kl = (int)((p >> 15) & (unsigned)(KB - 1));
            int pos = atomicAdd(&kcur[kl], 1);
            list2[pos - sub] = (int)(p & 0x7FFFu);
        }
        if (bucket == NBUK1 - 1 && tid == 0) ptr2[N_NODES] = NNZ;
    } else {
        // ---- gemm1 (R12 validated): C[M][64] = A[M][512] @ Bw[512][64] ----
        constexpr int BK = 32;
        float (*Ast)[BK + 4] = (float (*)[BK + 4])smem;          // 64x36 = 9216B
        float (*Bs)[HID + 4] = (float (*)[HID + 4])(smem + 9216); // 32x68 = 8704B
        int tx = tid & 15;
        int ty = tid >> 4;
        int row0 = (bid - NBUK0 - NBUK1) * 64;
        float acc[4][4] = {};
        int a_row = tid >> 3;
        int a_c4  = (tid & 7) * 4;
        int b_k   = tid >> 4;
        int b_c   = (tid & 15) * 4;
        for (int k0 = 0; k0 < F_IN; k0 += BK) {
#pragma unroll
            for (int l = 0; l < 2; ++l) {
                int row = a_row + 32 * l;
                int grow = row0 + row;
                float4 v = make_float4(0.f, 0.f, 0.f, 0.f);
                if (grow < M) v = *reinterpret_cast<const float4*>(&A[(size_t)grow * F_IN + k0 + a_c4]);
                *reinterpret_cast<float4*>(&Ast[row][a_c4]) = v;
            }
#pragma unroll
            for (int l = 0; l < 2; ++l) {
                int k = b_k + 16 * l;
                float4 w = *reinterpret_cast<const float4*>(&Bw[(size_t)(k0 + k) * HID + b_c]);
                *reinterpret_cast<float4*>(&Bs[k][b_c]) = w;
            }
            __syncthreads();
#pragma unroll
            for (int k = 0; k < BK; k += 4) {
                float4 a0 = *reinterpret_cast<const float4*>(&Ast[ty * 4 + 0][k]);
                float4 a1 = *reinterpret_cast<const float4*>(&Ast[ty * 4 + 1][k]);
                float4 a2 = *reinterpret_cast<const float4*>(&Ast[ty * 4 + 2][k]);
                float4 a3 = *reinterpret_cast<const float4*>(&Ast[ty * 4 + 3][k]);
                float4 b0 = *reinterpret_cast<const float4*>(&Bs[k + 0][tx * 4]);
                float4 b1 = *reinterpret_cast<const float4*>(&Bs[k + 1][tx * 4]);
                float4 b2 = *reinterpret_cast<const float4*>(&Bs[k + 2][tx * 4]);
                float4 b3 = *reinterpret_cast<const float4*>(&Bs[k + 3][tx * 4]);
                float a[4][4] = {{a0.x, a0.y, a0.z, a0.w},
                                 {a1.x, a1.y, a1.z, a1.w},
                                 {a2.x, a2.y, a2.z, a2.w},
                                 {a3.x, a3.y, a3.z, a3.w}};
                float b[4][4] = {{b0.x, b0.y, b0.z, b0.w},
                                 {b1.x, b1.y, b1.z, b1.w},
                                 {b2.x, b2.y, b2.z, b2.w},
                                 {b3.x, b3.y, b3.z, b3.w}};
#pragma unroll
                for (int s = 0; s < 4; ++s)
#pragma unroll
                    for (int i = 0; i < 4; ++i)
#pragma unroll
                        for (int j = 0; j < 4; ++j)
                            acc[i][j] += a[i][s] * b[s][j];
            }
            __syncthreads();
        }
#pragma unroll
        for (int i = 0; i < 4; ++i) {
            int row = row0 + ty * 4 + i;
            if (row < M) {
                float4 v = make_float4(acc[i][0], acc[i][1], acc[i][2], acc[i][3]);
                *reinterpret_cast<float4*>(&C[(size_t)row * HID + tx * 4]) = v;
            }
        }
    }
}

// ---------------------------------------------------------------------------
// Segment gather-sum (R12 validated): wave/segment, 4 groups of 16 lanes,
// depth-2 unroll = 32 rows in flight (depth-4 costs +51us via VGPR pressure,
// R14). All shuffles uniform across 64 lanes.
// ---------------------------------------------------------------------------
template <int PHASE>
__global__ __launch_bounds__(256) void seg_gather(const float* __restrict__ in,
                                                  float* __restrict__ out,
                                                  const int* __restrict__ ptr,
                                                  const int* __restrict__ list,
                                                  const float* __restrict__ scale,
                                                  const float* __restrict__ bias,
                                                  int nseg, int do_relu) {
    int gid = blockIdx.x * 256 + threadIdx.x;
    int seg = gid >> 6;
    int lane = gid & 63;
    if (seg >= nseg) return;
    int beg = ptr[seg], end = ptr[seg + 1];
    int g = lane >> 4, sub = lane & 15;
    const float4* in4 = reinterpret_cast<const float4*>(in);
    float4 acc = make_float4(0.f, 0.f, 0.f, 0.f);
    for (int j = beg; j < end; j += 64) {
        int cnt = end - j; if (cnt > 64) cnt = 64;
        int idx = (lane < cnt) ? list[j + lane] : 0;
        int full16 = cnt >> 4;
        int s = 0;
        for (; s + 2 <= full16; s += 2) {
            int r0 = 16 * s + g;
            int n0 = __shfl(idx, r0);
            int n1 = __shfl(idx, r0 + 4);
            int n2 = __shfl(idx, r0 + 8);
            int n3 = __shfl(idx, r0 + 12);
            int n4 = __shfl(idx, r0 + 16);
            int n5 = __shfl(idx, r0 + 20);
            int n6 = __shfl(idx, r0 + 24);
            int n7 = __shfl(idx, r0 + 28);
            float4 v0 = in4[(size_t)n0 * 16 + sub];
            float4 v1 = in4[(size_t)n1 * 16 + sub];
            float4 v2 = in4[(size_t)n2 * 16 + sub];
            float4 v3 = in4[(size_t)n3 * 16 + sub];
            float4 v4 = in4[(size_t)n4 * 16 + sub];
            float4 v5 = in4[(size_t)n5 * 16 + sub];
            float4 v6 = in4[(size_t)n6 * 16 + sub];
            float4 v7 = in4[(size_t)n7 * 16 + sub];
            acc.x += (v0.x + v1.x) + (v2.x + v3.x);
            acc.y += (v0.y + v1.y) + (v2.y + v3.y);
            acc.z += (v0.z + v1.z) + (v2.z + v3.z);
            acc.w += (v0.w + v1.w) + (v2.w + v3.w);
            acc.x += (v4.x + v5.x) + (v6.x + v7.x);
            acc.y += (v4.y + v5.y) + (v6.y + v7.y);
            acc.z += (v4.z + v5.z) + (v6.z + v7.z);
            acc.w += (v4.w + v5.w) + (v6.w + v7.w);
        }
        for (; s < full16; ++s) {
            int r0 = 16 * s + g;
            int n0 = __shfl(idx, r0);
            int n1 = __shfl(idx, r0 + 4);
            int n2 = __shfl(idx, r0 + 8);
            int n3 = __shfl(idx, r0 + 12);
            float4 v0 = in4[(size_t)n0 * 16 + sub];
            float4 v1 = in4[(size_t)n1 * 16 + sub];
            float4 v2 = in4[(size_t)n2 * 16 + sub];
            float4 v3 = in4[(size_t)n3 * 16 + sub];
            acc.x += (v0.x + v1.x) + (v2.x + v3.x);
            acc.y += (v0.y + v1.y) + (v2.y + v3.y);
            acc.z += (v0.z + v1.z) + (v2.z + v3.z);
            acc.w += (v0.w + v1.w) + (v2.w + v3.w);
        }
        int rem_start = full16 << 4;
        int nrem4 = (cnt - rem_start + 3) >> 2;
        for (int t = 0; t < nrem4; ++t) {
            int row = rem_start + 4 * t + g;
            int n = __shfl(idx, row < cnt ? row : 0);
            if (row < cnt) {
                float4 v = in4[(size_t)n * 16 + sub];
                acc.x += v.x; acc.y += v.y; acc.z += v.z; acc.w += v.w;
            }
        }
    }
    acc.x += __shfl_xor(acc.x, 16);
    acc.y += __shfl_xor(acc.y, 16);
    acc.z += __shfl_xor(acc.z, 16);
    acc.w += __shfl_xor(acc.w, 16);
    acc.x += __shfl_xor(acc.x, 32);
    acc.y += __shfl_xor(acc.y, 32);
    acc.z += __shfl_xor(acc.z, 32);
    acc.w += __shfl_xor(acc.w, 32);
    if (lane < 16) {
        float s = scale[seg];
        acc.x *= s; acc.y *= s; acc.z *= s; acc.w *= s;
        if (bias) {
            float4 b = reinterpret_cast<const float4*>(bias)[sub];
            acc.x += b.x; acc.y += b.y; acc.z += b.z; acc.w += b.w;
        }
        if (do_relu) {
            acc.x = fmaxf(acc.x, 0.f); acc.y = fmaxf(acc.y, 0.f);
            acc.z = fmaxf(acc.z, 0.f); acc.w = fmaxf(acc.w, 0.f);
        }
        reinterpret_cast<float4*>(out)[(size_t)seg * 16 + sub] = acc;
    }
}

// ---------------------------------------------------------------------------
// GEMM2 epilogue: out[M][70] = in[M][64] @ W2[64][70] + b2  (wave per row)
// (kept separate — R11 showed fusion into phase 3 regresses)
// ---------------------------------------------------------------------------
__global__ __launch_bounds__(256) void gemm2_kernel(const float* __restrict__ in,
                                                    const float* __restrict__ W2,
                                                    const float* __restrict__ b2,
                                                    float* __restrict__ out, int M) {
    __shared__ float Ws[HID][72];
    __shared__ float bs[72];
    __shared__ float rows[4][HID];
    int tid = threadIdx.x;
    for (int i = tid; i < HID * 72; i += 256) {
        int r = i / 72, c = i % 72;
        Ws[r][c] = (c < CLS) ? W2[r * CLS + c] : 0.f;
    }
    if (tid < 72) bs[tid] = (tid < CLS) ? b2[tid] : 0.f;
    int wid = tid >> 6, lane = tid & 63;
    int m = blockIdx.x * 4 + wid;
    if (m < M) rows[wid][lane] = in[(size_t)m * HID + lane];
    __syncthreads();
    if (m >= M) return;
    int c2 = 64 + (lane & 7);
    float acc0 = bs[lane];
    float acc1 = bs[c2];
#pragma unroll
    for (int k = 0; k < HID; ++k) {
        float xv = rows[wid][k];
        acc0 += xv * Ws[k][lane];
        acc1 += xv * Ws[k][c2];
    }
    out[(size_t)m * CLS + lane] = acc0;
    if (lane < 6) out[(size_t)m * CLS + 64 + lane] = acc1;
}

// ---------------------------------------------------------------------------
extern "C" void kernel_launch(void* const* d_in, const int* in_sizes, int n_in,
                              void* d_out, int out_size, void* d_ws, size_t ws_size,
                              hipStream_t stream) {
    const float* x   = (const float*)d_in[0];
    const int*   hid = (const int*)d_in[1];     // [2][NNZ] int32: row0=node, row1=edge
    const float* W1  = (const float*)d_in[2];
    const float* b1  = (const float*)d_in[3];
    const float* W2  = (const float*)d_in[4];
    const float* b2  = (const float*)d_in[5];
    float* out = (float*)d_out;

    size_t off = 0;
    auto alloc = [&](size_t bytes) {
        void* p = (char*)d_ws + off;
        off += (bytes + 255) & ~(size_t)255;
        return p;
    };
    int*   ptr1  = (int*)alloc((size_t)(N_EDGES + 1) * 4);
    int*   ptr2  = (int*)alloc((size_t)(N_NODES + 1) * 4);
    int*   bsum  = (int*)alloc(64 * 4);
    float* Binv  = (float*)alloc((size_t)N_EDGES * 4);
    float* Dinv  = (float*)alloc((size_t)N_NODES * 4);
    int*   list1 = (int*)alloc((size_t)NNZ * 4);
    int*   list2 = (int*)alloc((size_t)NNZ * 4);
    float* bufA  = (float*)alloc((size_t)N_NODES * HID * 4);   // xW1, later agg2
    float* bufB  = (float*)alloc((size_t)N_NODES * HID * 4);   // h1 (relu'd)
    float* he    = (float*)alloc((size_t)N_EDGES * HID * 4);   // edge features
    (void)ws_size; (void)n_in; (void)in_sizes; (void)out_size;

    // Build-time scratch aliases:
    //   hist/scanned in he (written by sg0 only after the build);
    //   bucketed = bufB (25.6MB exact; bufB first written by sg1) so that
    //   gemm1 (writes bufA) is independent of the bucket builds -> fusable.
    int*      hist     = (int*)he;
    int*      scanned  = (int*)((char*)he + (512 << 10));
    unsigned* bucketed = (unsigned*)bufB;

    const int NB_SCAN = (NHT + 2047) / 2048;   // 53

    // ---- fused build ----
    part_hist_both<<<NBA, 256, 0, stream>>>(hid, hist);
    scan_blocks<<<NB_SCAN, 256, 0, stream>>>(hist, scanned, bsum, NHT);
    scan_bsums<<<1, 64, 0, stream>>>(bsum, NB_SCAN);
    scan_apply<<<(NHT + 255) / 256, 256, 0, stream>>>(scanned, bsum, NHT);
    part_scatter_both<<<NBA, 256, 0, stream>>>(hid, scanned, bucketed);

    // ---- bb0 + bb1 + gemm1 co-scheduled (mutually independent tasks) ----
    build_gemm_fused<<<NBUK0 + NBUK1 + G1_BLOCKS, 256, 0, stream>>>(
        bucketed, scanned, ptr1, Binv, list1, ptr2, Dinv, list2,
        x, W1, bufA, N_NODES);

    // Layer 1: edge agg -> node agg (+b1, relu)
    seg_gather<0><<<(N_EDGES * 64) / 256, 256, 0, stream>>>(bufA, he, ptr1, list1, Binv, nullptr, N_EDGES, 0);
    seg_gather<1><<<(N_NODES * 64) / 256, 256, 0, stream>>>(he, bufB, ptr2, list2, Dinv, b1, N_NODES, 1);

    // Layer 2: edge agg -> node agg -> @W2 + b2 (separate epilogue kernel)
    seg_gather<2><<<(N_EDGES * 64) / 256, 256, 0, stream>>>(bufB, he, ptr1, list1, Binv, nullptr, N_EDGES, 0);
    seg_gather<3><<<(N_NODES * 64) / 256, 256, 0, stream>>>(he, bufA, ptr2, list2, Dinv, nullptr, N_NODES, 0);
    gemm2_kernel<<<(N_NODES + 3) / 4, 256, 0, stream>>>(bufA, W2, b2, out, N_NODES);
}

// Round 17
// 683.429 us; speedup vs baseline: 1.3810x; 1.0065x over previous
//
#include <hip/hip_runtime.h>
#include <hip/hip_bf16.h>

// Problem constants (match reference setup_inputs)
constexpr int N_NODES = 100000;
constexpr int N_EDGES = 20000;
constexpr int NNZ     = 3200000;
constexpr int F_IN    = 512;
constexpr int HID     = 64;
constexpr int CLS     = 70;

// CSR build via two-level counting sort, both directions fused.
constexpr int CHUNK = 32768;                         // entries per partition block
constexpr int NBA   = (NNZ + CHUNK - 1) / CHUNK;     // 98 partition blocks
constexpr int NBUK0 = (N_EDGES + 63) / 64;           // 313
constexpr int NBUK1 = (N_NODES + 127) / 128;         // 782
constexpr int NH0   = NBUK0 * NBA;                   // 30674
constexpr int NH1   = NBUK1 * NBA;                   // 76636
constexpr int NHT   = NH0 + NH1;                     // 107310 (concatenated)
constexpr int G1_BLOCKS = (N_NODES + 63) / 64;       // 1563 gemm1 row-blocks

// ---------------------------------------------------------------------------
// Pass A1 (fused): per-block LDS histograms for BOTH directions, one pass.
// ---------------------------------------------------------------------------
__global__ __launch_bounds__(256) void part_hist_both(const int* __restrict__ hidx,
                                                      int* __restrict__ hist) {
    __shared__ int cnt[NBUK0 + NBUK1];
    for (int b = threadIdx.x; b < NBUK0 + NBUK1; b += 256) cnt[b] = 0;
    __syncthreads();
    int base = blockIdx.x * CHUNK;
    int lim = NNZ - base; if (lim > CHUNK) lim = CHUNK;
    for (int i = threadIdx.x; i < lim; i += 256) {
        int s = hidx[base + i];
        int e = hidx[NNZ + base + i];
        atomicAdd(&cnt[e >> 6], 1);
        atomicAdd(&cnt[NBUK0 + (s >> 7)], 1);
    }
    __syncthreads();
    for (int b = threadIdx.x; b < NBUK0; b += 256)
        hist[b * NBA + blockIdx.x] = cnt[b];
    for (int b = threadIdx.x; b < NBUK1; b += 256)
        hist[NH0 + b * NBA + blockIdx.x] = cnt[NBUK0 + b];
}

// ---------------------------------------------------------------------------
// Generic exclusive scan: scan_blocks -> scan_bsums -> scan_apply
// ---------------------------------------------------------------------------
__global__ __launch_bounds__(256) void scan_blocks(const int* __restrict__ in,
                                                   int* __restrict__ out,
                                                   int* __restrict__ bsum, int n) {
    __shared__ int tmp[256];
    int base = blockIdx.x * 2048;
    int vals[8];
    int s = 0;
#pragma unroll
    for (int i = 0; i < 8; ++i) {
        int g = base + threadIdx.x * 8 + i;
        int v = (g < n) ? in[g] : 0;
        s += v;
        vals[i] = s;
    }
    tmp[threadIdx.x] = s;
    __syncthreads();
    for (int off = 1; off < 256; off <<= 1) {
        int v = 0;
        if (threadIdx.x >= off) v = tmp[threadIdx.x - off];
        __syncthreads();
        if (threadIdx.x >= off) tmp[threadIdx.x] += v;
        __syncthreads();
    }
    int prev = (threadIdx.x > 0) ? tmp[threadIdx.x - 1] : 0;
#pragma unroll
    for (int i = 0; i < 8; ++i) {
        int g = base + threadIdx.x * 8 + i;
        if (g < n) out[g + 1] = vals[i] + prev;
    }
    if (threadIdx.x == 255) bsum[blockIdx.x] = tmp[255];
}

__global__ __launch_bounds__(64) void scan_bsums(int* __restrict__ bsum, int nb) {
    int t = threadIdx.x;
    int v = (t < nb) ? bsum[t] : 0;
#pragma unroll
    for (int off = 1; off < 64; off <<= 1) {
        int u = __shfl_up(v, off);
        if (t >= off) v += u;
    }
    int ex = __shfl_up(v, 1);
    if (t == 0) ex = 0;
    if (t < nb) bsum[t] = ex;
}

__global__ __launch_bounds__(256) void scan_apply(int* __restrict__ out,
                                                  const int* __restrict__ bsum, int n) {
    int g = blockIdx.x * 256 + threadIdx.x;
    if (g >= n) return;
    out[g + 1] += bsum[g >> 11];
    if (g == 0) out[0] = 0;
}

// ---------------------------------------------------------------------------
// Pass A2 (fused): scatter BOTH packed directions in one pass over hidx.
// ---------------------------------------------------------------------------
__global__ __launch_bounds__(256) void part_scatter_both(const int* __restrict__ hidx,
                                                         const int* __restrict__ scanned,
                                                         unsigned* __restrict__ bucketed) {
    __shared__ int cur[NBUK0 + NBUK1];
    for (int b = threadIdx.x; b < NBUK0; b += 256)
        cur[b] = scanned[b * NBA + blockIdx.x];
    for (int b = threadIdx.x; b < NBUK1; b += 256)
        cur[NBUK0 + b] = scanned[NH0 + b * NBA + blockIdx.x];
    __syncthreads();
    int base = blockIdx.x * CHUNK;
    int lim = NNZ - base; if (lim > CHUNK) lim = CHUNK;
    for (int i = threadIdx.x; i < lim; i += 256) {
        int s = hidx[base + i];
        int e = hidx[NNZ + base + i];
        int pos0 = atomicAdd(&cur[e >> 6], 1);
        bucketed[pos0] = ((unsigned)e << 17) | (unsigned)s;
        int pos1 = atomicAdd(&cur[NBUK0 + (s >> 7)], 1);
        bucketed[pos1] = ((unsigned)s << 15) | (unsigned)e;
    }
}

// ---------------------------------------------------------------------------
// FUSED independent-task kernel: blocks [0,313) run bucket_build0 (granule
// sort), [313,1095) run bucket_build1, [1095,2658) run gemm1. Tasks are
// mutually independent; co-scheduling hides the bucket builds under gemm1.
// launch_bounds(256, 6): VGPR cap ~85 so the gemm path's natural ~56-68
// VGPRs fit WITHOUT spill (R16's (256,8)=64-cap produced VGPR=32 + ~90MB
// scratch-spill writes); LDS 17.9KB still allows 6 blocks/CU.
// ---------------------------------------------------------------------------
__global__ __launch_bounds__(256, 6) void build_gemm_fused(
        const unsigned* __restrict__ bucketed,
        const int* __restrict__ scanned,
        int* __restrict__ ptr1, float* __restrict__ Binv, int* __restrict__ list1,
        int* __restrict__ ptr2, float* __restrict__ Dinv, int* __restrict__ list2,
        const float* __restrict__ A, const float* __restrict__ Bw,
        float* __restrict__ C, int M) {
    __shared__ __align__(16) char smem[17920];
    int bid = blockIdx.x;
    int tid = threadIdx.x;
    if (bid < NBUK0) {
        // ---- bucket_build0: 64 edges x 16 node-granules (node>>13) ----
        int* kcnt = (int*)smem;            // 1024
        int* koff = kcnt + 1024;           // 1025
        int* kcur = koff + 1025;           // 1024
        int* tmp  = kcur + 1024;           // 256   (13316B total)
        constexpr int NSB = 64 * 16;
        int bucket = bid;
        int start = scanned[bucket * NBA];
        int end   = scanned[(bucket + 1) * NBA];
        for (int k = tid; k < NSB; k += 256) kcnt[k] = 0;
        __syncthreads();
        for (int i = start + tid; i < end; i += 256) {
            unsigned p = bucketed[i];
            int e_loc = (int)((p >> 17) & 63u);
            int n     = (int)(p & 0x1FFFFu);
            atomicAdd(&kcnt[e_loc * 16 + (n >> 13)], 1);
        }
        __syncthreads();
        int b4 = tid * 4;
        int v0 = kcnt[b4], v1 = kcnt[b4 + 1], v2 = kcnt[b4 + 2], v3 = kcnt[b4 + 3];
        int s = v0 + v1 + v2 + v3;
        tmp[tid] = s;
        __syncthreads();
        for (int off = 1; off < 256; off <<= 1) {
            int u = 0;
            if (tid >= off) u = tmp[tid - off];
            __syncthreads();
            if (tid >= off) tmp[tid] += u;
            __syncthreads();
        }
        int prev = (tid > 0) ? tmp[tid - 1] : 0;
        koff[b4]     = prev;
        koff[b4 + 1] = prev + v0;
        koff[b4 + 2] = prev + v0 + v1;
        koff[b4 + 3] = prev + v0 + v1 + v2;
        if (tid == 255) koff[NSB] = tmp[255];
        __syncthreads();
        if (tid < 64) {
            int key = bucket * 64 + tid;
            if (key < N_EDGES) {
                int o0 = koff[tid * 16];
                int o1 = koff[tid * 16 + 16];
                ptr1[key] = start + o0;
                int d = o1 - o0;
                Binv[key] = (d > 0) ? 1.0f / (float)d : 0.0f;
            }
        }
        for (int k = tid; k < NSB; k += 256) kcur[k] = start + koff[k];
        __syncthreads();
        for (int i = start + tid; i < end; i += 256) {
            unsigned p = bucketed[i];
            int e_loc = (int)((p >> 17) & 63u);
            int n     = (int)(p & 0x1FFFFu);
            int pos = atomicAdd(&kcur[e_loc * 16 + (n >> 13)], 1);
            list1[pos] = n;
        }
        if (bucket == NBUK0 - 1 && tid == 0) ptr1[N_EDGES] = NNZ;
    } else if (bid < NBUK0 + NBUK1) {
        // ---- bucket_build1 ----
        constexpr int KB = 128;
        int* kcnt = (int*)smem;            // 128
        int* koff = kcnt + 128;            // 129
        int* kcur = koff + 129;            // 128
        const int* sc = scanned + NH0;
        int bucket = bid - NBUK0;
        int sub = NNZ;
        int start = sc[bucket * NBA];
        int end   = sc[(bucket + 1) * NBA];
        for (int k = tid; k < KB; k += 256) kcnt[k] = 0;
        __syncthreads();
        for (int i = start + tid; i < end; i += 256) {
            int kl = (int)((bucketed[i] >> 15) & (unsigned)(KB - 1));
            atomicAdd(&kcnt[kl], 1);
        }
        __syncthreads();
        if (tid == 0) {
            int s = 0;
#pragma unroll 8
            for (int k = 0; k < KB; ++k) { koff[k] = s; s += kcnt[k]; }
            koff[KB] = s;
        }
        __syncthreads();
        if (tid < KB) {
            int key = bucket * KB + tid;
            int base = start + koff[tid];
            if (key < N_NODES) {
                ptr2[key] = base - sub;
                int d = kcnt[tid];
                Dinv[key] = (d > 0) ? 1.0f / (float)d : 0.0f;
            }
            kcur[tid] = base;
        }
        __syncthreads();
        for (int i = start + tid; i < end; i += 256) {
            unsigned p = bucketed[i];
            int kl = (int)((p >> 15) & (unsigned)(KB - 1));
            int pos = atomicAdd(&kcur[kl], 1);
            list2[pos - sub] = (int)(p & 0x7FFFu);
        }
        if (bucket == NBUK1 - 1 && tid == 0) ptr2[N_NODES] = NNZ;
    } else {
        // ---- gemm1 (R12 validated): C[M][64] = A[M][512] @ Bw[512][64] ----
        constexpr int BK = 32;
        float (*Ast)[BK + 4] = (float (*)[BK + 4])smem;          // 64x36 = 9216B
        float (*Bs)[HID + 4] = (float (*)[HID + 4])(smem + 9216); // 32x68 = 8704B
        int tx = tid & 15;
        int ty = tid >> 4;
        int row0 = (bid - NBUK0 - NBUK1) * 64;
        float acc[4][4] = {};
        int a_row = tid >> 3;
        int a_c4  = (tid & 7) * 4;
        int b_k   = tid >> 4;
        int b_c   = (tid & 15) * 4;
        for (int k0 = 0; k0 < F_IN; k0 += BK) {
#pragma unroll
            for (int l = 0; l < 2; ++l) {
                int row = a_row + 32 * l;
                int grow = row0 + row;
                float4 v = make_float4(0.f, 0.f, 0.f, 0.f);
                if (grow < M) v = *reinterpret_cast<const float4*>(&A[(size_t)grow * F_IN + k0 + a_c4]);
                *reinterpret_cast<float4*>(&Ast[row][a_c4]) = v;
            }
#pragma unroll
            for (int l = 0; l < 2; ++l) {
                int k = b_k + 16 * l;
                float4 w = *reinterpret_cast<const float4*>(&Bw[(size_t)(k0 + k) * HID + b_c]);
                *reinterpret_cast<float4*>(&Bs[k][b_c]) = w;
            }
            __syncthreads();
#pragma unroll
            for (int k = 0; k < BK; k += 4) {
                float4 a0 = *reinterpret_cast<const float4*>(&Ast[ty * 4 + 0][k]);
                float4 a1 = *reinterpret_cast<const float4*>(&Ast[ty * 4 + 1][k]);
                float4 a2 = *reinterpret_cast<const float4*>(&Ast[ty * 4 + 2][k]);
                float4 a3 = *reinterpret_cast<const float4*>(&Ast[ty * 4 + 3][k]);
                float4 b0 = *reinterpret_cast<const float4*>(&Bs[k + 0][tx * 4]);
                float4 b1 = *reinterpret_cast<const float4*>(&Bs[k + 1][tx * 4]);
                float4 b2 = *reinterpret_cast<const float4*>(&Bs[k + 2][tx * 4]);
                float4 b3 = *reinterpret_cast<const float4*>(&Bs[k + 3][tx * 4]);
                float a[4][4] = {{a0.x, a0.y, a0.z, a0.w},
                                 {a1.x, a1.y, a1.z, a1.w},
                                 {a2.x, a2.y, a2.z, a2.w},
                                 {a3.x, a3.y, a3.z, a3.w}};
                float b[4][4] = {{b0.x, b0.y, b0.z, b0.w},
                                 {b1.x, b1.y, b1.z, b1.w},
                                 {b2.x, b2.y, b2.z, b2.w},
                                 {b3.x, b3.y, b3.z, b3.w}};
#pragma unroll
                for (int s = 0; s < 4; ++s)
#pragma unroll
                    for (int i = 0; i < 4; ++i)
#pragma unroll
                        for (int j = 0; j < 4; ++j)
                            acc[i][j] += a[i][s] * b[s][j];
            }
            __syncthreads();
        }
#pragma unroll
        for (int i = 0; i < 4; ++i) {
            int row = row0 + ty * 4 + i;
            if (row < M) {
                float4 v = make_float4(acc[i][0], acc[i][1], acc[i][2], acc[i][3]);
                *reinterpret_cast<float4*>(&C[(size_t)row * HID + tx * 4]) = v;
            }
        }
    }
}

// ---------------------------------------------------------------------------
// Segment gather-sum (R12 validated): wave/segment, 4 groups of 16 lanes,
// depth-2 unroll = 32 rows in flight (depth-4 costs +51us via VGPR pressure,
// R14). All shuffles uniform across 64 lanes.
// ---------------------------------------------------------------------------
template <int PHASE>
__global__ __launch_bounds__(256) void seg_gather(const float* __restrict__ in,
                                                  float* __restrict__ out,
                                                  const int* __restrict__ ptr,
                                                  const int* __restrict__ list,
                                                  const float* __restrict__ scale,
                                                  const float* __restrict__ bias,
                                                  int nseg, int do_relu) {
    int gid = blockIdx.x * 256 + threadIdx.x;
    int seg = gid >> 6;
    int lane = gid & 63;
    if (seg >= nseg) return;
    int beg = ptr[seg], end = ptr[seg + 1];
    int g = lane >> 4, sub = lane & 15;
    const float4* in4 = reinterpret_cast<const float4*>(in);
    float4 acc = make_float4(0.f, 0.f, 0.f, 0.f);
    for (int j = beg; j < end; j += 64) {
        int cnt = end - j; if (cnt > 64) cnt = 64;
        int idx = (lane < cnt) ? list[j + lane] : 0;
        int full16 = cnt >> 4;
        int s = 0;
        for (; s + 2 <= full16; s += 2) {
            int r0 = 16 * s + g;
            int n0 = __shfl(idx, r0);
            int n1 = __shfl(idx, r0 + 4);
            int n2 = __shfl(idx, r0 + 8);
            int n3 = __shfl(idx, r0 + 12);
            int n4 = __shfl(idx, r0 + 16);
            int n5 = __shfl(idx, r0 + 20);
            int n6 = __shfl(idx, r0 + 24);
            int n7 = __shfl(idx, r0 + 28);
            float4 v0 = in4[(size_t)n0 * 16 + sub];
            float4 v1 = in4[(size_t)n1 * 16 + sub];
            float4 v2 = in4[(size_t)n2 * 16 + sub];
            float4 v3 = in4[(size_t)n3 * 16 + sub];
            float4 v4 = in4[(size_t)n4 * 16 + sub];
            float4 v5 = in4[(size_t)n5 * 16 + sub];
            float4 v6 = in4[(size_t)n6 * 16 + sub];
            float4 v7 = in4[(size_t)n7 * 16 + sub];
            acc.x += (v0.x + v1.x) + (v2.x + v3.x);
            acc.y += (v0.y + v1.y) + (v2.y + v3.y);
            acc.z += (v0.z + v1.z) + (v2.z + v3.z);
            acc.w += (v0.w + v1.w) + (v2.w + v3.w);
            acc.x += (v4.x + v5.x) + (v6.x + v7.x);
            acc.y += (v4.y + v5.y) + (v6.y + v7.y);
            acc.z += (v4.z + v5.z) + (v6.z + v7.z);
            acc.w += (v4.w + v5.w) + (v6.w + v7.w);
        }
        for (; s < full16; ++s) {
            int r0 = 16 * s + g;
            int n0 = __shfl(idx, r0);
            int n1 = __shfl(idx, r0 + 4);
            int n2 = __shfl(idx, r0 + 8);
            int n3 = __shfl(idx, r0 + 12);
            float4 v0 = in4[(size_t)n0 * 16 + sub];
            float4 v1 = in4[(size_t)n1 * 16 + sub];
            float4 v2 = in4[(size_t)n2 * 16 + sub];
            float4 v3 = in4[(size_t)n3 * 16 + sub];
            acc.x += (v0.x + v1.x) + (v2.x + v3.x);
            acc.y += (v0.y + v1.y) + (v2.y + v3.y);
            acc.z += (v0.z + v1.z) + (v2.z + v3.z);
            acc.w += (v0.w + v1.w) + (v2.w + v3.w);
        }
        int rem_start = full16 << 4;
        int nrem4 = (cnt - rem_start + 3) >> 2;
        for (int t = 0; t < nrem4; ++t) {
            int row = rem_start + 4 * t + g;
            int n = __shfl(idx, row < cnt ? row : 0);
            if (row < cnt) {
                float4 v = in4[(size_t)n * 16 + sub];
                acc.x += v.x; acc.y += v.y; acc.z += v.z; acc.w += v.w;
            }
        }
    }
    acc.x += __shfl_xor(acc.x, 16);
    acc.y += __shfl_xor(acc.y, 16);
    acc.z += __shfl_xor(acc.z, 16);
    acc.w += __shfl_xor(acc.w, 16);
    acc.x += __shfl_xor(acc.x, 32);
    acc.y += __shfl_xor(acc.y, 32);
    acc.z += __shfl_xor(acc.z, 32);
    acc.w += __shfl_xor(acc.w, 32);
    if (lane < 16) {
        float s = scale[seg];
        acc.x *= s; acc.y *= s; acc.z *= s; acc.w *= s;
        if (bias) {
            float4 b = reinterpret_cast<const float4*>(bias)[sub];
            acc.x += b.x; acc.y += b.y; acc.z += b.z; acc.w += b.w;
        }
        if (do_relu) {
            acc.x = fmaxf(acc.x, 0.f); acc.y = fmaxf(acc.y, 0.f);
            acc.z = fmaxf(acc.z, 0.f); acc.w = fmaxf(acc.w, 0.f);
        }
        reinterpret_cast<float4*>(out)[(size_t)seg * 16 + sub] = acc;
    }
}

// ---------------------------------------------------------------------------
// GEMM2 epilogue: out[M][70] = in[M][64] @ W2[64][70] + b2  (wave per row)
// (kept separate — R11 showed fusion into phase 3 regresses)
// ---------------------------------------------------------------------------
__global__ __launch_bounds__(256) void gemm2_kernel(const float* __restrict__ in,
                                                    const float* __restrict__ W2,
                                                    const float* __restrict__ b2,
                                                    float* __restrict__ out, int M) {
    __shared__ float Ws[HID][72];
    __shared__ float bs[72];
    __shared__ float rows[4][HID];
    int tid = threadIdx.x;
    for (int i = tid; i < HID * 72; i += 256) {
        int r = i / 72, c = i % 72;
        Ws[r][c] = (c < CLS) ? W2[r * CLS + c] : 0.f;
    }
    if (tid < 72) bs[tid] = (tid < CLS) ? b2[tid] : 0.f;
    int wid = tid >> 6, lane = tid & 63;
    int m = blockIdx.x * 4 + wid;
    if (m < M) rows[wid][lane] = in[(size_t)m * HID + lane];
    __syncthreads();
    if (m >= M) return;
    int c2 = 64 + (lane & 7);
    float acc0 = bs[lane];
    float acc1 = bs[c2];
#pragma unroll
    for (int k = 0; k < HID; ++k) {
        float xv = rows[wid][k];
        acc0 += xv * Ws[k][lane];
        acc1 += xv * Ws[k][c2];
    }
    out[(size_t)m * CLS + lane] = acc0;
    if (lane < 6) out[(size_t)m * CLS + 64 + lane] = acc1;
}

// ---------------------------------------------------------------------------
extern "C" void kernel_launch(void* const* d_in, const int* in_sizes, int n_in,
                              void* d_out, int out_size, void* d_ws, size_t ws_size,
                              hipStream_t stream) {
    const float* x   = (const float*)d_in[0];
    const int*   hid = (const int*)d_in[1];     // [2][NNZ] int32: row0=node, row1=edge
    const float* W1  = (const float*)d_in[2];
    const float* b1  = (const float*)d_in[3];
    const float* W2  = (const float*)d_in[4];
    const float* b2  = (const float*)d_in[5];
    float* out = (float*)d_out;

    size_t off = 0;
    auto alloc = [&](size_t bytes) {
        void* p = (char*)d_ws + off;
        off += (bytes + 255) & ~(size_t)255;
        return p;
    };
    int*   ptr1  = (int*)alloc((size_t)(N_EDGES + 1) * 4);
    int*   ptr2  = (int*)alloc((size_t)(N_NODES + 1) * 4);
    int*   bsum  = (int*)alloc(64 * 4);
    float* Binv  = (float*)alloc((size_t)N_EDGES * 4);
    float* Dinv  = (float*)alloc((size_t)N_NODES * 4);
    int*   list1 = (int*)alloc((size_t)NNZ * 4);
    int*   list2 = (int*)alloc((size_t)NNZ * 4);
    float* bufA  = (float*)alloc((size_t)N_NODES * HID * 4);   // xW1, later agg2
    float* bufB  = (float*)alloc((size_t)N_NODES * HID * 4);   // h1 (relu'd)
    float* he    = (float*)alloc((size_t)N_EDGES * HID * 4);   // edge features
    (void)ws_size; (void)n_in; (void)in_sizes; (void)out_size;

    // Build-time scratch aliases:
    //   hist/scanned in he (written by sg0 only after the build);
    //   bucketed = bufB (25.6MB exact; bufB first written by sg1) so that
    //   gemm1 (writes bufA) is independent of the bucket builds -> fusable.
    int*      hist     = (int*)he;
    int*      scanned  = (int*)((char*)he + (512 << 10));
    unsigned* bucketed = (unsigned*)bufB;

    const int NB_SCAN = (NHT + 2047) / 2048;   // 53

    // ---- fused build ----
    part_hist_both<<<NBA, 256, 0, stream>>>(hid, hist);
    scan_blocks<<<NB_SCAN, 256, 0, stream>>>(hist, scanned, bsum, NHT);
    scan_bsums<<<1, 64, 0, stream>>>(bsum, NB_SCAN);
    scan_apply<<<(NHT + 255) / 256, 256, 0, stream>>>(scanned, bsum, NHT);
    part_scatter_both<<<NBA, 256, 0, stream>>>(hid, scanned, bucketed);

    // ---- bb0 + bb1 + gemm1 co-scheduled (mutually independent tasks) ----
    build_gemm_fused<<<NBUK0 + NBUK1 + G1_BLOCKS, 256, 0, stream>>>(
        bucketed, scanned, ptr1, Binv, list1, ptr2, Dinv, list2,
        x, W1, bufA, N_NODES);

    // Layer 1: edge agg -> node agg (+b1, relu)
    seg_gather<0><<<(N_EDGES * 64) / 256, 256, 0, stream>>>(bufA, he, ptr1, list1, Binv, nullptr, N_EDGES, 0);
    seg_gather<1><<<(N_NODES * 64) / 256, 256, 0, stream>>>(he, bufB, ptr2, list2, Dinv, b1, N_NODES, 1);

    // Layer 2: edge agg -> node agg -> @W2 + b2 (separate epilogue kernel)
    seg_gather<2><<<(N_EDGES * 64) / 256, 256, 0, stream>>>(bufB, he, ptr1, list1, Binv, nullptr, N_EDGES, 0);
    seg_gather<3><<<(N_NODES * 64) / 256, 256, 0, stream>>>(he, bufA, ptr2, list2, Dinv, nullptr, N_NODES, 0);
    gemm2_kernel<<<(N_NODES + 3) / 4, 256, 0, stream>>>(bufA, W2, b2, out, N_NODES);
}